// Round 12
// baseline (970.381 us; speedup 1.0000x reference)
//
#include <hip/hip_runtime.h>
#include <hip/hip_bf16.h>

#define NBMAX 256   // coarse buckets per direction
#define TILE  4096  // edges per staged-scatter tile (per-dir fallback)
#define KPT   16    // TILE / 256
#define FTILE 2048  // edges per fused-scatter tile
#define FKPT  8     // FTILE / 256
#define BINSMAX 512 // max fine bins per bucket

// seg(student) in [0,8): near-uniform 8-way split via magic multiply
__device__ __forceinline__ int seg8(unsigned r, unsigned mult8) {
    return (int)__umulhi(r, mult8);
}

// ---------------- A1: coarse histogram, all 4 dirs (LDS-privatized) ---------
__global__ __launch_bounds__(256) void hist_all(
        const int* __restrict__ k0, const int* __restrict__ k1,
        const int* __restrict__ k2, const int* __restrict__ k3,
        int* __restrict__ gcnt4, int nnz, int rsh_s, int rsh_p) {
    __shared__ int h[NBMAX];
    int dir = blockIdx.x & 3;
    const int* key = (dir == 0) ? k0 : (dir == 1) ? k1 : (dir == 2) ? k2 : k3;
    int rsh = (dir & 1) ? rsh_p : rsh_s;
    h[threadIdx.x] = 0;
    __syncthreads();
    int ch = blockIdx.x >> 2, nch = gridDim.x >> 2;
    int nnz4 = nnz >> 2;
    for (int i = ch * 256 + threadIdx.x; i < nnz4; i += nch * 256) {
        int4 k4 = ((const int4*)key)[i];
        atomicAdd(&h[k4.x >> rsh], 1);
        atomicAdd(&h[k4.y >> rsh], 1);
        atomicAdd(&h[k4.z >> rsh], 1);
        atomicAdd(&h[k4.w >> rsh], 1);
    }
    if (ch == 0) {
        for (int i = (nnz4 << 2) + threadIdx.x; i < nnz; i += 256)
            atomicAdd(&h[key[i] >> rsh], 1);
    }
    __syncthreads();
    int v = h[threadIdx.x];
    if (v) atomicAdd(&gcnt4[dir * NBMAX + threadIdx.x], v);
}

// ---------------- A2: bucket offsets for all 4 dirs (4 blocks) --------------
__global__ __launch_bounds__(256) void scan_all(
        const int* __restrict__ gcnt4, int* __restrict__ boffs4,
        int* __restrict__ bcur4, int nb_s, int nb_p, int nnz,
        int* __restrict__ offsE, int* __restrict__ offsO, int NS, int NP8) {
    __shared__ int tmp[NBMAX];
    int dir = blockIdx.x, tid = threadIdx.x;
    int nb = (dir & 1) ? nb_p : nb_s;
    int v = (tid < nb) ? gcnt4[dir * NBMAX + tid] : 0;
    tmp[tid] = v;
    __syncthreads();
    for (int off = 1; off < NBMAX; off <<= 1) {
        int t = (tid >= off) ? tmp[tid - off] : 0;
        __syncthreads();
        tmp[tid] += t;
        __syncthreads();
    }
    if (tid < nb) {
        int e = tmp[tid] - v;
        boffs4[dir * (NBMAX + 1) + tid] = e;
        bcur4[dir * NBMAX + tid] = e;
    }
    if (tid == 0) boffs4[dir * (NBMAX + 1) + nb] = nnz;
    if (dir == 0 && tid == 0) { offsE[NS] = nnz; offsO[NP8] = nnz; }
}

// ---------------- A3a: per-dir staged scatter (fallback when ws is tight) ---
__global__ __launch_bounds__(256) void staged_scatter(
        const int* __restrict__ key, const int* __restrict__ other,
        const float* __restrict__ vals, int* __restrict__ cursor,
        uint2* __restrict__ edges, int nnz, int rsh) {
    __shared__ int lhist[NBMAX], lofs[NBMAX], lbase[NBMAX];
    __shared__ uint2 stage[TILE];
    __shared__ int   sslot[TILE];
    int tid = threadIdx.x;
    int lmask = (1 << rsh) - 1;
    int ntiles = (nnz + TILE - 1) / TILE;
    for (int tile = blockIdx.x; tile < ntiles; tile += gridDim.x) {
        int tbeg = tile * TILE;
        int n = nnz - tbeg; if (n > TILE) n = TILE;
        lhist[tid] = 0;
        __syncthreads();
        int myb[KPT], myr[KPT]; unsigned myo[KPT]; float myv[KPT];
        #pragma unroll
        for (int g = 0; g < 4; ++g) {
            int s = g * 1024 + tid * 4;
            if (s + 4 <= n) {
                int i = tbeg + s;
                int4   k4 = *(const int4*)(key + i);
                int4   o4 = *(const int4*)(other + i);
                float4 v4 = *(const float4*)(vals + i);
                int   kk[4] = {k4.x, k4.y, k4.z, k4.w};
                int   oo[4] = {o4.x, o4.y, o4.z, o4.w};
                float vv[4] = {v4.x, v4.y, v4.z, v4.w};
                #pragma unroll
                for (int k = 0; k < 4; ++k) {
                    int m = g * 4 + k;
                    myb[m] = kk[k] >> rsh;
                    myo[m] = (unsigned)oo[k] | ((unsigned)(kk[k] & lmask) << 16);
                    myv[m] = vv[k];
                    myr[m] = atomicAdd(&lhist[myb[m]], 1);
                }
            } else {
                #pragma unroll
                for (int k = 0; k < 4; ++k) {
                    int m = g * 4 + k;
                    int s2 = s + k;
                    if (s2 < n) {
                        int i = tbeg + s2;
                        int ky = key[i];
                        myb[m] = ky >> rsh;
                        myo[m] = (unsigned)other[i] | ((unsigned)(ky & lmask) << 16);
                        myv[m] = vals[i];
                        myr[m] = atomicAdd(&lhist[myb[m]], 1);
                    } else myb[m] = -1;
                }
            }
        }
        __syncthreads();
        int h = lhist[tid];
        lofs[tid] = h;
        __syncthreads();
        for (int off = 1; off < NBMAX; off <<= 1) {
            int t = (tid >= off) ? lofs[tid - off] : 0;
            __syncthreads();
            lofs[tid] += t;
            __syncthreads();
        }
        lofs[tid] -= h;
        if (h > 0) lbase[tid] = atomicAdd(&cursor[tid], h);
        __syncthreads();
        #pragma unroll
        for (int k = 0; k < KPT; ++k) {
            if (myb[k] >= 0) {
                int ls = lofs[myb[k]] + myr[k];
                stage[ls] = make_uint2(myo[k], __float_as_uint(myv[k]));
                sslot[ls] = lbase[myb[k]] + myr[k];
            }
        }
        __syncthreads();
        #pragma unroll
        for (int k = 0; k < KPT; ++k) {
            int s = k * 256 + tid;
            if (s < n) edges[sslot[s]] = stage[s];
        }
        __syncthreads();
    }
}

// ---------------- A3b: FUSED scatter (r10 two-buffer form) + fine counts ----
// One read of (rows,cols,vals) feeds BOTH directions. r11 lesson: do NOT
// phase-split the staging (barrier vmcnt-drain serializes the E/O write
// streams; overlap > occupancy here). NEW: 2 fire-and-forget global atomics
// per edge produce the FINE bin counts (even: per-row; odd: per col*8+seg)
// so the fine sort's counting pass (a full 25.6MB edge stream) disappears.
// Scatter2 is latency-bound (VALU 5%) - the extra issue slots are free.
__global__ __launch_bounds__(256) void staged_scatter2(
        const int* __restrict__ krow, const int* __restrict__ kcol,
        const float* __restrict__ vals,
        int* __restrict__ curE, int* __restrict__ curO,
        uint2* __restrict__ edgesE, uint2* __restrict__ edgesO,
        int* __restrict__ fineE, int* __restrict__ fineO,
        int nnz, int rsh_e, int rsh_o, unsigned mult8) {
    __shared__ int lhistE[NBMAX], lofsE[NBMAX], lbaseE[NBMAX];
    __shared__ int lhistO[NBMAX], lofsO[NBMAX], lbaseO[NBMAX];
    __shared__ uint2 stageE[FTILE], stageO[FTILE];
    __shared__ int   sslotE[FTILE], sslotO[FTILE];
    int tid = threadIdx.x;
    int lmE = (1 << rsh_e) - 1, lmO = (1 << rsh_o) - 1;
    int ntiles = (nnz + FTILE - 1) / FTILE;
    for (int tile = blockIdx.x; tile < ntiles; tile += gridDim.x) {
        int tbeg = tile * FTILE;
        int n = nnz - tbeg; if (n > FTILE) n = FTILE;
        lhistE[tid] = 0; lhistO[tid] = 0;
        __syncthreads();
        int mbE[FKPT], mrE[FKPT]; unsigned moE[FKPT];
        int mbO[FKPT], mrO[FKPT]; unsigned moO[FKPT];
        float mv[FKPT];
        #pragma unroll
        for (int g = 0; g < 2; ++g) {
            int s = g * 1024 + tid * 4;           // 4 consecutive edges/thread
            if (s + 4 <= n) {
                int i = tbeg + s;
                int4   r4 = *(const int4*)(krow + i);
                int4   c4 = *(const int4*)(kcol + i);
                float4 v4 = *(const float4*)(vals + i);
                int   rr[4] = {r4.x, r4.y, r4.z, r4.w};
                int   cc[4] = {c4.x, c4.y, c4.z, c4.w};
                float vv[4] = {v4.x, v4.y, v4.z, v4.w};
                #pragma unroll
                for (int k = 0; k < 4; ++k) {
                    int m = g * 4 + k;
                    mv[m]  = vv[k];
                    mbE[m] = rr[k] >> rsh_e;
                    moE[m] = (unsigned)cc[k] | ((unsigned)(rr[k] & lmE) << 16);
                    mrE[m] = atomicAdd(&lhistE[mbE[m]], 1);
                    mbO[m] = cc[k] >> rsh_o;
                    moO[m] = (unsigned)rr[k] | ((unsigned)(cc[k] & lmO) << 16);
                    mrO[m] = atomicAdd(&lhistO[mbO[m]], 1);
                    atomicAdd(&fineE[rr[k]], 1);
                    atomicAdd(&fineO[cc[k] * 8 + seg8((unsigned)rr[k], mult8)], 1);
                }
            } else {
                #pragma unroll
                for (int k = 0; k < 4; ++k) {
                    int m = g * 4 + k;
                    int s2 = s + k;
                    if (s2 < n) {
                        int i = tbeg + s2;
                        int r = krow[i], c = kcol[i];
                        mv[m]  = vals[i];
                        mbE[m] = r >> rsh_e;
                        moE[m] = (unsigned)c | ((unsigned)(r & lmE) << 16);
                        mrE[m] = atomicAdd(&lhistE[mbE[m]], 1);
                        mbO[m] = c >> rsh_o;
                        moO[m] = (unsigned)r | ((unsigned)(c & lmO) << 16);
                        mrO[m] = atomicAdd(&lhistO[mbO[m]], 1);
                        atomicAdd(&fineE[r], 1);
                        atomicAdd(&fineO[c * 8 + seg8((unsigned)r, mult8)], 1);
                    } else { mbE[m] = -1; mbO[m] = -1; }
                }
            }
        }
        __syncthreads();
        int hE = lhistE[tid], hO = lhistO[tid];
        lofsE[tid] = hE; lofsO[tid] = hO;
        __syncthreads();
        for (int off = 1; off < NBMAX; off <<= 1) {
            int tE = (tid >= off) ? lofsE[tid - off] : 0;
            int tO = (tid >= off) ? lofsO[tid - off] : 0;
            __syncthreads();
            lofsE[tid] += tE; lofsO[tid] += tO;
            __syncthreads();
        }
        lofsE[tid] -= hE; lofsO[tid] -= hO;
        if (hE > 0) lbaseE[tid] = atomicAdd(&curE[tid], hE);
        if (hO > 0) lbaseO[tid] = atomicAdd(&curO[tid], hO);
        __syncthreads();
        #pragma unroll
        for (int k = 0; k < FKPT; ++k) {
            if (mbE[k] >= 0) {
                int lsE = lofsE[mbE[k]] + mrE[k];
                stageE[lsE] = make_uint2(moE[k], __float_as_uint(mv[k]));
                sslotE[lsE] = lbaseE[mbE[k]] + mrE[k];
                int lsO = lofsO[mbO[k]] + mrO[k];
                stageO[lsO] = make_uint2(moO[k], __float_as_uint(mv[k]));
                sslotO[lsO] = lbaseO[mbO[k]] + mrO[k];
            }
        }
        __syncthreads();
        #pragma unroll
        for (int k = 0; k < FKPT; ++k) {
            int s = k * 256 + tid;
            if (s < n) {
                edgesE[sslotE[s]] = stageE[s];
                edgesO[sslotO[s]] = stageO[s];
            }
        }
        __syncthreads();
    }
}

// ---------------- B (fallback): one block per bucket, 2-pass fine sort ------
__global__ __launch_bounds__(512) void row_sort1(
        const uint2* __restrict__ e1, uint2* __restrict__ e2,
        const int* __restrict__ boffs, int* __restrict__ offs,
        int odd, int nb, int rsh, int nrows, unsigned mult8) {
    __shared__ int cnt[BINSMAX];                   // counts, then cursors
    __shared__ int tot[512];
    int tid = threadIdx.x;
    int b = blockIdx.x;
    if (b >= nb) return;
    int bins = odd ? (8 << rsh) : (1 << rsh);      // <= 512
    int beg = boffs[b], end = boffs[b + 1];
    if (tid < bins) cnt[tid] = 0;
    __syncthreads();
    for (int i = beg + tid; i < end; i += 512) {
        uint2 e = e1[i];
        int lrow = (int)(e.x >> 16);
        int bin = odd ? (lrow * 8 + seg8(e.x & 0xFFFFu, mult8)) : lrow;
        atomicAdd(&cnt[bin], 1);
    }
    __syncthreads();
    int own = (tid < bins) ? cnt[tid] : 0;
    tot[tid] = own;
    __syncthreads();
    for (int off = 1; off < 512; off <<= 1) {
        int t = (tid >= off) ? tot[tid - off] : 0;
        __syncthreads();
        tot[tid] += t;
        __syncthreads();
    }
    if (tid < bins) {
        int fineoff = tot[tid] - own;              // exclusive within bucket
        cnt[tid] = beg + fineoff;                  // becomes cursor
        if (!odd) {
            int row = (b << rsh) + tid;
            if (row < nrows) offs[row] = beg + fineoff;
        } else {
            int row = (b << rsh) + (tid >> 3);
            if (row < nrows) offs[(row << 3) + (tid & 7)] = beg + fineoff;
        }
    }
    __syncthreads();
    for (int i = beg + tid; i < end; i += 512) {
        uint2 e = e1[i];
        int lrow = (int)(e.x >> 16);
        int bin = odd ? (lrow * 8 + seg8(e.x & 0xFFFFu, mult8)) : lrow;
        int slot = atomicAdd(&cnt[bin], 1);
        e2[slot] = make_uint2(e.x & 0xFFFFu, e.y);
    }
}

// ---------------- B (fused): single-pass sort using precomputed fine counts -
// Counts come from staged_scatter2's global atomics (in the offs array);
// this kernel converts them IN PLACE to CSR offsets, then scatters in ONE
// edge pass (vs 2) - the counting stream (25.6MB/dispatch) is eliminated.
__global__ __launch_bounds__(512) void row_sort1g(
        const uint2* __restrict__ e1, uint2* __restrict__ e2,
        const int* __restrict__ boffs, int* __restrict__ offs,
        int odd, int nb, int rsh, int nrows, unsigned mult8) {
    __shared__ int cnt[BINSMAX];                   // cursors
    __shared__ int tot[512];
    int tid = threadIdx.x;
    int b = blockIdx.x;
    if (b >= nb) return;
    int bins = odd ? (8 << rsh) : (1 << rsh);      // <= 512
    int beg = boffs[b], end = boffs[b + 1];
    int own = 0;
    if (tid < bins) {
        if (!odd) {
            int row = (b << rsh) + tid;
            own = (row < nrows) ? offs[row] : 0;
        } else {
            int row = (b << rsh) + (tid >> 3);
            own = (row < nrows) ? offs[(row << 3) + (tid & 7)] : 0;
        }
    }
    tot[tid] = own;
    __syncthreads();
    for (int off = 1; off < 512; off <<= 1) {
        int t = (tid >= off) ? tot[tid - off] : 0;
        __syncthreads();
        tot[tid] += t;
        __syncthreads();
    }
    if (tid < bins) {
        int fineoff = tot[tid] - own;              // exclusive within bucket
        cnt[tid] = beg + fineoff;                  // cursor
        if (!odd) {
            int row = (b << rsh) + tid;
            if (row < nrows) offs[row] = beg + fineoff;
        } else {
            int row = (b << rsh) + (tid >> 3);
            if (row < nrows) offs[(row << 3) + (tid & 7)] = beg + fineoff;
        }
    }
    __syncthreads();
    for (int i = beg + tid; i < end; i += 512) {
        uint2 e = e1[i];
        int lrow = (int)(e.x >> 16);
        int bin = odd ? (lrow * 8 + seg8(e.x & 0xFFFFu, mult8)) : lrow;
        int slot = atomicAdd(&cnt[bin], 1);
        e2[slot] = make_uint2(e.x & 0xFFFFu, e.y);
    }
}

// ---------------- gather core (r8 form - L2-BW-pinned, do not touch) --------
__device__ __forceinline__ void chunk_accum(
        float4& acc, uint2 e, int n, const float* __restrict__ xq, int q) {
    int   c0 = __shfl((int)e.x, q);
    float v0 = __uint_as_float(__shfl((int)e.y, q));
    int   c1 = __shfl((int)e.x, 4 + q);
    float v1 = __uint_as_float(__shfl((int)e.y, 4 + q));
    float4 x0 = *(const float4*)(xq + (((size_t)c0) << 6));
    float4 x1 = *(const float4*)(xq + (((size_t)c1) << 6));
    for (int j = 8; j < n; j += 8) {
        int   nc0 = __shfl((int)e.x, j + q);
        float nv0 = __uint_as_float(__shfl((int)e.y, j + q));
        int   nc1 = __shfl((int)e.x, j + 4 + q);
        float nv1 = __uint_as_float(__shfl((int)e.y, j + 4 + q));
        float4 nx0 = *(const float4*)(xq + (((size_t)nc0) << 6));
        float4 nx1 = *(const float4*)(xq + (((size_t)nc1) << 6));
        acc.x += v0 * x0.x; acc.y += v0 * x0.y;
        acc.z += v0 * x0.z; acc.w += v0 * x0.w;
        acc.x += v1 * x1.x; acc.y += v1 * x1.y;
        acc.z += v1 * x1.z; acc.w += v1 * x1.w;
        v0 = nv0; v1 = nv1; x0 = nx0; x1 = nx1;
    }
    acc.x += v0 * x0.x; acc.y += v0 * x0.y;
    acc.z += v0 * x0.z; acc.w += v0 * x0.w;
    acc.x += v1 * x1.x; acc.y += v1 * x1.y;
    acc.z += v1 * x1.z; acc.w += v1 * x1.w;
}

__device__ __forceinline__ float4 gather_pre(
        uint2 e0, int beg, int end, const uint2* __restrict__ edges,
        const float* __restrict__ xq, int q, int lane) {
    float4 acc = make_float4(0.f, 0.f, 0.f, 0.f);
    int n0 = end - beg; if (n0 > 64) n0 = 64;
    chunk_accum(acc, e0, n0, xq, q);              // empty bin: e0 zero -> +0
    for (int base = beg + 64; base < end; base += 64) {
        int n = end - base; if (n > 64) n = 64;
        uint2 e = make_uint2(0u, 0u);
        if (lane < n) e = edges[base + lane];
        chunk_accum(acc, e, n, xq, q);
    }
    acc.x += __shfl_xor(acc.x, 16); acc.y += __shfl_xor(acc.y, 16);
    acc.z += __shfl_xor(acc.z, 16); acc.w += __shfl_xor(acc.w, 16);
    acc.x += __shfl_xor(acc.x, 32); acc.y += __shfl_xor(acc.y, 32);
    acc.z += __shfl_xor(acc.z, 32); acc.w += __shfl_xor(acc.w, 32);
    return acc;
}

// ---------------- C-even: per-row wave gather, 2 rows/wave pipelined --------
__global__ __launch_bounds__(256) void row_gather(
        const int* __restrict__ offs, const uint2* __restrict__ edges,
        const float* __restrict__ x, float* __restrict__ out, int nrows) {
    int wave = threadIdx.x >> 6, lane = threadIdx.x & 63;
    int q = lane >> 4, l16 = lane & 15;
    const float* xq = x + (l16 << 2);
    int rA = blockIdx.x * 8 + wave * 2;
    if (rA >= nrows) return;
    int rB = rA + 1;
    int begA = offs[rA], endA = offs[rA + 1];
    int begB = 0, endB = 0;
    if (rB < nrows) { begB = offs[rB]; endB = offs[rB + 1]; }
    int nA = endA - begA; if (nA > 64) nA = 64;
    int nB = endB - begB; if (nB > 64) nB = 64;
    uint2 eA = make_uint2(0u, 0u), eB = make_uint2(0u, 0u);
    if (lane < nA) eA = edges[begA + lane];
    if (lane < nB) eB = edges[begB + lane];     // in flight during A's compute
    float4 accA = gather_pre(eA, begA, endA, edges, xq, q, lane);
    if ((lane >> 4) == 0)
        *(float4*)(out + (((size_t)rA) << 6) + (l16 << 2)) = accA;
    if (rB < nrows) {
        float4 accB = gather_pre(eB, begB, endB, edges, xq, q, lane);
        if ((lane >> 4) == 0)
            *(float4*)(out + (((size_t)rB) << 6) + (l16 << 2)) = accB;
    }
}

// ---------------- C-odd: XCD-partitioned gather, 2 bins/wave pipelined ------
__global__ __launch_bounds__(256) void xcd_gather(
        const int* __restrict__ offs, const uint2* __restrict__ edges,
        const float* __restrict__ x, float* __restrict__ partial, int NP) {
    int g = blockIdx.x;
    int slot = g & 7;
    int t = g >> 3;
    int wave = threadIdx.x >> 6, lane = threadIdx.x & 63;
    int q = lane >> 4, l16 = lane & 15;
    const float* xq = x + (l16 << 2);
    int rA = t * 8 + wave * 2;
    if (rA >= NP) return;
    int rB = rA + 1;
    int binA = rA * 8 + slot;
    int begA = offs[binA], endA = offs[binA + 1];
    int begB = 0, endB = 0;
    if (rB < NP) { int binB = rB * 8 + slot; begB = offs[binB]; endB = offs[binB + 1]; }
    int nA = endA - begA; if (nA > 64) nA = 64;
    int nB = endB - begB; if (nB > 64) nB = 64;
    uint2 eA = make_uint2(0u, 0u), eB = make_uint2(0u, 0u);
    if (lane < nA) eA = edges[begA + lane];
    if (lane < nB) eB = edges[begB + lane];     // in flight during A's compute
    float4 accA = gather_pre(eA, begA, endA, edges, xq, q, lane);
    if ((lane >> 4) == 0)
        *(float4*)(partial + (size_t)slot * NP * 64 + (((size_t)rA) << 6) + (l16 << 2)) = accA;
    if (rB < NP) {
        float4 accB = gather_pre(eB, begB, endB, edges, xq, q, lane);
        if ((lane >> 4) == 0)
            *(float4*)(partial + (size_t)slot * NP * 64 + (((size_t)rB) << 6) + (l16 << 2)) = accB;
    }
}

__global__ __launch_bounds__(256) void reduce8(
        const float* __restrict__ partial, float* __restrict__ out, int n4) {
    int i = blockIdx.x * 256 + threadIdx.x;
    if (i < n4) {
        const float4* p = (const float4*)partial;
        float4 s = make_float4(0.f, 0.f, 0.f, 0.f);
        #pragma unroll
        for (int xx = 0; xx < 8; ++xx) {
            float4 v = p[(size_t)xx * n4 + i];
            s.x += v.x; s.y += v.y; s.z += v.z; s.w += v.w;
        }
        ((float4*)out)[i] = s;
    }
}

// ---------------- fallback: atomic scatter ----------------
__global__ void spmm_scatter_kernel(const int* __restrict__ rows, const int* __restrict__ cols,
                                    const float* __restrict__ vals,
                                    const float* __restrict__ s_emb, const float* __restrict__ p_emb,
                                    float* __restrict__ out_s, float* __restrict__ out_p, int nnz) {
    long long t = (long long)blockIdx.x * blockDim.x + threadIdx.x;
    int e = (int)(t >> 6);
    int d = (int)(t & 63);
    if (e >= nnz) return;
    int r = rows[e];
    int c = cols[e];
    float v = vals[e];
    atomicAdd(&out_s[(size_t)r * 64 + d], v * p_emb[(size_t)c * 64 + d]);
    atomicAdd(&out_p[(size_t)c * 64 + d], v * s_emb[(size_t)r * 64 + d]);
}

// ---------------- host ----------------
extern "C" void kernel_launch(void* const* d_in, const int* in_sizes, int n_in,
                              void* d_out, int out_size, void* d_ws, size_t ws_size,
                              hipStream_t stream) {
    const float* s_emb   = (const float*)d_in[0];
    const float* p_emb   = (const float*)d_in[1];
    const int*   a_rows  = (const int*)d_in[2];
    const int*   a_cols  = (const int*)d_in[3];
    const float* a_vals  = (const float*)d_in[4];
    const int*   ia_rows = (const int*)d_in[5];
    const int*   ia_cols = (const int*)d_in[6];
    const float* ia_vals = (const float*)d_in[7];

    const int NS  = in_sizes[0] / 64;
    const int NP  = in_sizes[1] / 64;
    const int nnz = in_sizes[2];
    const int NP8 = NP * 8;

    float* out = (float*)d_out;
    float* out_sc  = out;
    float* out_sic = out_sc  + (size_t)NS * 64;
    float* out_pc  = out_sic + (size_t)NS * 64;
    float* out_pic = out_pc  + (size_t)NP * 64;

    int rsh_s = 0; while ((((long long)NS + (1LL << rsh_s) - 1) >> rsh_s) > NBMAX) rsh_s++;
    int rsh_p = 0; while ((((long long)NP + (1LL << rsh_p) - 1) >> rsh_p) > NBMAX) rsh_p++;
    int nb_s = (NS + (1 << rsh_s) - 1) >> rsh_s;
    int nb_p = (NP + (1 << rsh_p) - 1) >> rsh_p;
    unsigned mult8 = (unsigned)((8ULL << 32) / (unsigned)NS);

    const size_t edges_bytes = (size_t)nnz * sizeof(uint2);
    const size_t offsE_bytes = (size_t)(NS + 1) * sizeof(int);
    const size_t offsO_bytes = (size_t)(NP8 + 1) * sizeof(int);
    const size_t fixed_bytes = offsE_bytes + offsO_bytes
                      + (size_t)(4 * NBMAX + 4 * (NBMAX + 1) + 4 * NBMAX) * sizeof(int) + 256;
    const size_t need  = 2 * edges_bytes + fixed_bytes;
    const size_t need3 = 3 * edges_bytes + fixed_bytes;
    const bool packable = (NS <= 0xFFFF) && (NP <= 0xFFFF) &&
                          ((1 << rsh_s) <= BINSMAX) && ((8 << rsh_p) <= BINSMAX) &&
                          (edges_bytes >= (size_t)NP8 * 64 * sizeof(float)) &&
                          ((NP * 64) % 4 == 0);

    if (ws_size < need || !packable) {
        hipMemsetAsync(d_out, 0, (size_t)out_size * sizeof(float), stream);
        const long long total = (long long)nnz * 64;
        const int grid = (int)((total + 255) / 256);
        spmm_scatter_kernel<<<grid, 256, 0, stream>>>(a_rows, a_cols, a_vals, s_emb, p_emb,
                                                      out_sc, out_pc, nnz);
        spmm_scatter_kernel<<<grid, 256, 0, stream>>>(ia_rows, ia_cols, ia_vals, s_emb, p_emb,
                                                      out_sic, out_pic, nnz);
        return;
    }

    const bool fused = (ws_size >= need3);

    char* w = (char*)d_ws;
    uint2* edges1 = (uint2*)w;  w += edges_bytes;
    uint2* edges2 = (uint2*)w;  w += edges_bytes;
    uint2* edges3 = nullptr;
    if (fused) { edges3 = (uint2*)w; w += edges_bytes; }
    int*   offsE  = (int*)w;    w += offsE_bytes;
    int*   offsO  = (int*)w;    w += offsO_bytes;
    int*   gcnt4  = (int*)w;    w += 4 * NBMAX * sizeof(int);
    int*   boffs4 = (int*)w;    w += 4 * (NBMAX + 1) * sizeof(int);
    int*   bcur4  = (int*)w;

    hipMemsetAsync(gcnt4, 0, 4 * NBMAX * sizeof(int), stream);
    // dirs: 0 = a by row, 1 = a by col, 2 = ia by row, 3 = ia by col
    hist_all<<<1024, 256, 0, stream>>>(a_rows, a_cols, ia_rows, ia_cols,
                                       gcnt4, nnz, rsh_s, rsh_p);
    scan_all<<<4, 256, 0, stream>>>(gcnt4, boffs4, bcur4, nb_s, nb_p, nnz,
                                    offsE, offsO, NS, NP8);

    if (fused) {
        const int ntiles2 = (nnz + FTILE - 1) / FTILE;
        struct Mat { const int* r; const int* c; const float* v;
                     float* oe; float* oo; int de, dodd; };
        Mat mats[2] = {
            { a_rows,  a_cols,  a_vals,  out_sc,  out_pc,  0, 1 },
            { ia_rows, ia_cols, ia_vals, out_sic, out_pic, 2, 3 },
        };
        for (int m = 0; m < 2; ++m) {
            const Mat& M = mats[m];
            // zero fine-count arrays (sentinels at [NS]/[NP8] preserved)
            hipMemsetAsync(offsE, 0, (size_t)NS * sizeof(int), stream);
            hipMemsetAsync(offsO, 0, (size_t)NP8 * sizeof(int), stream);
            // one pass over (rows,cols,vals): even buckets -> e1, odd -> e3,
            // fine counts -> offsE/offsO
            staged_scatter2<<<ntiles2, 256, 0, stream>>>(M.r, M.c, M.v,
                    bcur4 + M.de * NBMAX, bcur4 + M.dodd * NBMAX,
                    edges1, edges3, offsE, offsO, nnz, rsh_s, rsh_p, mult8);
            row_sort1g<<<nb_s, 512, 0, stream>>>(edges1, edges2,
                    boffs4 + M.de * (NBMAX + 1), offsE, 0, nb_s, rsh_s, NS, mult8);
            row_gather<<<(NS + 7) / 8, 256, 0, stream>>>(offsE, edges2, p_emb, M.oe, NS);
            row_sort1g<<<nb_p, 512, 0, stream>>>(edges3, edges1,
                    boffs4 + M.dodd * (NBMAX + 1), offsO, 1, nb_p, rsh_p, NP, mult8);
            xcd_gather<<<8 * ((NP + 7) / 8), 256, 0, stream>>>(offsO, edges1,
                    s_emb, (float*)edges3, NP);
            reduce8<<<(NP * 64 / 4 + 255) / 256, 256, 0, stream>>>((float*)edges3,
                    M.oo, NP * 64 / 4);
        }
        return;
    }

    // ---- non-fused (ws-tight) path: r8 structure ----
    float* partial = (float*)edges1;
    const int ntiles = (nnz + TILE - 1) / TILE;
    struct Dir { const int* key; const int* other; const float* vals;
                 float* out; int odd; };
    Dir dirs[4] = {
        { a_rows,  a_cols,  a_vals,  out_sc,  0 },
        { a_cols,  a_rows,  a_vals,  out_pc,  1 },
        { ia_rows, ia_cols, ia_vals, out_sic, 0 },
        { ia_cols, ia_rows, ia_vals, out_pic, 1 },
    };
    for (int t = 0; t < 4; ++t) {
        const Dir& D = dirs[t];
        if (!D.odd) {
            staged_scatter<<<ntiles, 256, 0, stream>>>(D.key, D.other, D.vals,
                                                       bcur4 + t * NBMAX, edges1, nnz, rsh_s);
            row_sort1<<<nb_s, 512, 0, stream>>>(edges1, edges2,
                                                boffs4 + t * (NBMAX + 1), offsE,
                                                0, nb_s, rsh_s, NS, mult8);
            row_gather<<<(NS + 7) / 8, 256, 0, stream>>>(offsE, edges2, p_emb, D.out, NS);
        } else {
            staged_scatter<<<ntiles, 256, 0, stream>>>(D.key, D.other, D.vals,
                                                       bcur4 + t * NBMAX, edges1, nnz, rsh_p);
            row_sort1<<<nb_p, 512, 0, stream>>>(edges1, edges2,
                                                boffs4 + t * (NBMAX + 1), offsO,
                                                1, nb_p, rsh_p, NP, mult8);
            xcd_gather<<<8 * ((NP + 7) / 8), 256, 0, stream>>>(offsO, edges2,
                                                               s_emb, partial, NP);
            reduce8<<<(NP * 64 / 4 + 255) / 256, 256, 0, stream>>>(partial, D.out, NP * 64 / 4);
        }
    }
}

// Round 13
// 579.615 us; speedup vs baseline: 1.6742x; 1.6742x over previous
//
#include <hip/hip_runtime.h>
#include <hip/hip_bf16.h>

#define NBMAX 256   // coarse buckets per direction
#define TILE  4096  // edges per staged-scatter tile (per-dir fallback)
#define KPT   16    // TILE / 256
#define FTILE 2048  // edges per fused-scatter tile
#define FKPT  8     // FTILE / 256
#define BINSMAX 512 // max fine bins per bucket

// seg(student) in [0,8): near-uniform 8-way split via magic multiply
__device__ __forceinline__ int seg8(unsigned r, unsigned mult8) {
    return (int)__umulhi(r, mult8);
}

// ---------------- A1: coarse histogram, all 4 dirs (LDS-privatized) ---------
__global__ __launch_bounds__(256) void hist_all(
        const int* __restrict__ k0, const int* __restrict__ k1,
        const int* __restrict__ k2, const int* __restrict__ k3,
        int* __restrict__ gcnt4, int nnz, int rsh_s, int rsh_p) {
    __shared__ int h[NBMAX];
    int dir = blockIdx.x & 3;
    const int* key = (dir == 0) ? k0 : (dir == 1) ? k1 : (dir == 2) ? k2 : k3;
    int rsh = (dir & 1) ? rsh_p : rsh_s;
    h[threadIdx.x] = 0;
    __syncthreads();
    int ch = blockIdx.x >> 2, nch = gridDim.x >> 2;
    int nnz4 = nnz >> 2;
    for (int i = ch * 256 + threadIdx.x; i < nnz4; i += nch * 256) {
        int4 k4 = ((const int4*)key)[i];
        atomicAdd(&h[k4.x >> rsh], 1);
        atomicAdd(&h[k4.y >> rsh], 1);
        atomicAdd(&h[k4.z >> rsh], 1);
        atomicAdd(&h[k4.w >> rsh], 1);
    }
    if (ch == 0) {
        for (int i = (nnz4 << 2) + threadIdx.x; i < nnz; i += 256)
            atomicAdd(&h[key[i] >> rsh], 1);
    }
    __syncthreads();
    int v = h[threadIdx.x];
    if (v) atomicAdd(&gcnt4[dir * NBMAX + threadIdx.x], v);
}

// ---------------- A2: bucket offsets for all 4 dirs (4 blocks) --------------
__global__ __launch_bounds__(256) void scan_all(
        const int* __restrict__ gcnt4, int* __restrict__ boffs4,
        int* __restrict__ bcur4, int nb_s, int nb_p, int nnz,
        int* __restrict__ offsE, int* __restrict__ offsO, int NS, int NP8) {
    __shared__ int tmp[NBMAX];
    int dir = blockIdx.x, tid = threadIdx.x;
    int nb = (dir & 1) ? nb_p : nb_s;
    int v = (tid < nb) ? gcnt4[dir * NBMAX + tid] : 0;
    tmp[tid] = v;
    __syncthreads();
    for (int off = 1; off < NBMAX; off <<= 1) {
        int t = (tid >= off) ? tmp[tid - off] : 0;
        __syncthreads();
        tmp[tid] += t;
        __syncthreads();
    }
    if (tid < nb) {
        int e = tmp[tid] - v;
        boffs4[dir * (NBMAX + 1) + tid] = e;
        bcur4[dir * NBMAX + tid] = e;
    }
    if (tid == 0) boffs4[dir * (NBMAX + 1) + nb] = nnz;
    if (dir == 0 && tid == 0) { offsE[NS] = nnz; offsO[NP8] = nnz; }
}

// ---------------- A3a: per-dir staged scatter (fallback when ws is tight) ---
__global__ __launch_bounds__(256) void staged_scatter(
        const int* __restrict__ key, const int* __restrict__ other,
        const float* __restrict__ vals, int* __restrict__ cursor,
        uint2* __restrict__ edges, int nnz, int rsh) {
    __shared__ int lhist[NBMAX], lofs[NBMAX], lbase[NBMAX];
    __shared__ uint2 stage[TILE];
    __shared__ int   sslot[TILE];
    int tid = threadIdx.x;
    int lmask = (1 << rsh) - 1;
    int ntiles = (nnz + TILE - 1) / TILE;
    for (int tile = blockIdx.x; tile < ntiles; tile += gridDim.x) {
        int tbeg = tile * TILE;
        int n = nnz - tbeg; if (n > TILE) n = TILE;
        lhist[tid] = 0;
        __syncthreads();
        int myb[KPT], myr[KPT]; unsigned myo[KPT]; float myv[KPT];
        #pragma unroll
        for (int g = 0; g < 4; ++g) {
            int s = g * 1024 + tid * 4;
            if (s + 4 <= n) {
                int i = tbeg + s;
                int4   k4 = *(const int4*)(key + i);
                int4   o4 = *(const int4*)(other + i);
                float4 v4 = *(const float4*)(vals + i);
                int   kk[4] = {k4.x, k4.y, k4.z, k4.w};
                int   oo[4] = {o4.x, o4.y, o4.z, o4.w};
                float vv[4] = {v4.x, v4.y, v4.z, v4.w};
                #pragma unroll
                for (int k = 0; k < 4; ++k) {
                    int m = g * 4 + k;
                    myb[m] = kk[k] >> rsh;
                    myo[m] = (unsigned)oo[k] | ((unsigned)(kk[k] & lmask) << 16);
                    myv[m] = vv[k];
                    myr[m] = atomicAdd(&lhist[myb[m]], 1);
                }
            } else {
                #pragma unroll
                for (int k = 0; k < 4; ++k) {
                    int m = g * 4 + k;
                    int s2 = s + k;
                    if (s2 < n) {
                        int i = tbeg + s2;
                        int ky = key[i];
                        myb[m] = ky >> rsh;
                        myo[m] = (unsigned)other[i] | ((unsigned)(ky & lmask) << 16);
                        myv[m] = vals[i];
                        myr[m] = atomicAdd(&lhist[myb[m]], 1);
                    } else myb[m] = -1;
                }
            }
        }
        __syncthreads();
        int h = lhist[tid];
        lofs[tid] = h;
        __syncthreads();
        for (int off = 1; off < NBMAX; off <<= 1) {
            int t = (tid >= off) ? lofs[tid - off] : 0;
            __syncthreads();
            lofs[tid] += t;
            __syncthreads();
        }
        lofs[tid] -= h;
        if (h > 0) lbase[tid] = atomicAdd(&cursor[tid], h);
        __syncthreads();
        #pragma unroll
        for (int k = 0; k < KPT; ++k) {
            if (myb[k] >= 0) {
                int ls = lofs[myb[k]] + myr[k];
                stage[ls] = make_uint2(myo[k], __float_as_uint(myv[k]));
                sslot[ls] = lbase[myb[k]] + myr[k];
            }
        }
        __syncthreads();
        #pragma unroll
        for (int k = 0; k < KPT; ++k) {
            int s = k * 256 + tid;
            if (s < n) edges[sslot[s]] = stage[s];
        }
        __syncthreads();
    }
}

// ---------------- A3b: FUSED scatter (r10 two-buffer form, proven 61.7us) ---
// One read of (rows,cols,vals) feeds BOTH directions. r11: do NOT phase-split
// (barrier vmcnt-drain serializes E/O write streams). r12: do NOT add global
// fine-count atomics (cross-XCD atomics bypass L2 -> +200MB HBM writes).
__global__ __launch_bounds__(256) void staged_scatter2(
        const int* __restrict__ krow, const int* __restrict__ kcol,
        const float* __restrict__ vals,
        int* __restrict__ curE, int* __restrict__ curO,
        uint2* __restrict__ edgesE, uint2* __restrict__ edgesO,
        int nnz, int rsh_e, int rsh_o) {
    __shared__ int lhistE[NBMAX], lofsE[NBMAX], lbaseE[NBMAX];
    __shared__ int lhistO[NBMAX], lofsO[NBMAX], lbaseO[NBMAX];
    __shared__ uint2 stageE[FTILE], stageO[FTILE];
    __shared__ int   sslotE[FTILE], sslotO[FTILE];
    int tid = threadIdx.x;
    int lmE = (1 << rsh_e) - 1, lmO = (1 << rsh_o) - 1;
    int ntiles = (nnz + FTILE - 1) / FTILE;
    for (int tile = blockIdx.x; tile < ntiles; tile += gridDim.x) {
        int tbeg = tile * FTILE;
        int n = nnz - tbeg; if (n > FTILE) n = FTILE;
        lhistE[tid] = 0; lhistO[tid] = 0;
        __syncthreads();
        int mbE[FKPT], mrE[FKPT]; unsigned moE[FKPT];
        int mbO[FKPT], mrO[FKPT]; unsigned moO[FKPT];
        float mv[FKPT];
        #pragma unroll
        for (int g = 0; g < 2; ++g) {
            int s = g * 1024 + tid * 4;           // 4 consecutive edges/thread
            if (s + 4 <= n) {
                int i = tbeg + s;
                int4   r4 = *(const int4*)(krow + i);
                int4   c4 = *(const int4*)(kcol + i);
                float4 v4 = *(const float4*)(vals + i);
                int   rr[4] = {r4.x, r4.y, r4.z, r4.w};
                int   cc[4] = {c4.x, c4.y, c4.z, c4.w};
                float vv[4] = {v4.x, v4.y, v4.z, v4.w};
                #pragma unroll
                for (int k = 0; k < 4; ++k) {
                    int m = g * 4 + k;
                    mv[m]  = vv[k];
                    mbE[m] = rr[k] >> rsh_e;
                    moE[m] = (unsigned)cc[k] | ((unsigned)(rr[k] & lmE) << 16);
                    mrE[m] = atomicAdd(&lhistE[mbE[m]], 1);
                    mbO[m] = cc[k] >> rsh_o;
                    moO[m] = (unsigned)rr[k] | ((unsigned)(cc[k] & lmO) << 16);
                    mrO[m] = atomicAdd(&lhistO[mbO[m]], 1);
                }
            } else {
                #pragma unroll
                for (int k = 0; k < 4; ++k) {
                    int m = g * 4 + k;
                    int s2 = s + k;
                    if (s2 < n) {
                        int i = tbeg + s2;
                        int r = krow[i], c = kcol[i];
                        mv[m]  = vals[i];
                        mbE[m] = r >> rsh_e;
                        moE[m] = (unsigned)c | ((unsigned)(r & lmE) << 16);
                        mrE[m] = atomicAdd(&lhistE[mbE[m]], 1);
                        mbO[m] = c >> rsh_o;
                        moO[m] = (unsigned)r | ((unsigned)(c & lmO) << 16);
                        mrO[m] = atomicAdd(&lhistO[mbO[m]], 1);
                    } else { mbE[m] = -1; mbO[m] = -1; }
                }
            }
        }
        __syncthreads();
        int hE = lhistE[tid], hO = lhistO[tid];
        lofsE[tid] = hE; lofsO[tid] = hO;
        __syncthreads();
        for (int off = 1; off < NBMAX; off <<= 1) {
            int tE = (tid >= off) ? lofsE[tid - off] : 0;
            int tO = (tid >= off) ? lofsO[tid - off] : 0;
            __syncthreads();
            lofsE[tid] += tE; lofsO[tid] += tO;
            __syncthreads();
        }
        lofsE[tid] -= hE; lofsO[tid] -= hO;
        if (hE > 0) lbaseE[tid] = atomicAdd(&curE[tid], hE);
        if (hO > 0) lbaseO[tid] = atomicAdd(&curO[tid], hO);
        __syncthreads();
        #pragma unroll
        for (int k = 0; k < FKPT; ++k) {
            if (mbE[k] >= 0) {
                int lsE = lofsE[mbE[k]] + mrE[k];
                stageE[lsE] = make_uint2(moE[k], __float_as_uint(mv[k]));
                sslotE[lsE] = lbaseE[mbE[k]] + mrE[k];
                int lsO = lofsO[mbO[k]] + mrO[k];
                stageO[lsO] = make_uint2(moO[k], __float_as_uint(mv[k]));
                sslotO[lsO] = lbaseO[mbO[k]] + mrO[k];
            }
        }
        __syncthreads();
        #pragma unroll
        for (int k = 0; k < FKPT; ++k) {
            int s = k * 256 + tid;
            if (s < n) {
                edgesE[sslotE[s]] = stageE[s];
                edgesO[sslotO[s]] = stageO[s];
            }
        }
        __syncthreads();
    }
}

// ---------------- B (fallback): one block per bucket, 2-pass fine sort ------
__global__ __launch_bounds__(512) void row_sort1(
        const uint2* __restrict__ e1, uint2* __restrict__ e2,
        const int* __restrict__ boffs, int* __restrict__ offs,
        int odd, int nb, int rsh, int nrows, unsigned mult8) {
    __shared__ int cnt[BINSMAX];                   // counts, then cursors
    __shared__ int tot[512];
    int tid = threadIdx.x;
    int b = blockIdx.x;
    if (b >= nb) return;
    int bins = odd ? (8 << rsh) : (1 << rsh);      // <= 512
    int beg = boffs[b], end = boffs[b + 1];
    if (tid < bins) cnt[tid] = 0;
    __syncthreads();
    for (int i = beg + tid; i < end; i += 512) {
        uint2 e = e1[i];
        int lrow = (int)(e.x >> 16);
        int bin = odd ? (lrow * 8 + seg8(e.x & 0xFFFFu, mult8)) : lrow;
        atomicAdd(&cnt[bin], 1);
    }
    __syncthreads();
    int own = (tid < bins) ? cnt[tid] : 0;
    tot[tid] = own;
    __syncthreads();
    for (int off = 1; off < 512; off <<= 1) {
        int t = (tid >= off) ? tot[tid - off] : 0;
        __syncthreads();
        tot[tid] += t;
        __syncthreads();
    }
    if (tid < bins) {
        int fineoff = tot[tid] - own;              // exclusive within bucket
        cnt[tid] = beg + fineoff;                  // becomes cursor
        if (!odd) {
            int row = (b << rsh) + tid;
            if (row < nrows) offs[row] = beg + fineoff;
        } else {
            int row = (b << rsh) + (tid >> 3);
            if (row < nrows) offs[(row << 3) + (tid & 7)] = beg + fineoff;
        }
    }
    __syncthreads();
    for (int i = beg + tid; i < end; i += 512) {
        uint2 e = e1[i];
        int lrow = (int)(e.x >> 16);
        int bin = odd ? (lrow * 8 + seg8(e.x & 0xFFFFu, mult8)) : lrow;
        int slot = atomicAdd(&cnt[bin], 1);
        e2[slot] = make_uint2(e.x & 0xFFFFu, e.y);
    }
}

// ---------------- B (fused): 2 slices/bucket fine sort ----------------------
// row_sort1 launches only nb (196/157) blocks < 256 CUs -> >30% of the chip
// idle. 2 fused slices double block count (392/314) with NO global exchange:
// each block histograms the full bucket into split lo/hi counts, so the s=1
// block derives its cursor base (= lo[bin]) locally. Cost: 3 reads + 1 write
// per edge (vs 2+1); parallelism 2x. (r2: 8 slices/9 visits = 48us; r8:
// 1 block/2 visits = 39us; r3's global-exchange split regressed.)
__global__ __launch_bounds__(512) void row_sort2(
        const uint2* __restrict__ e1, uint2* __restrict__ e2,
        const int* __restrict__ boffs, int* __restrict__ offs,
        int odd, int nb, int rsh, int nrows, unsigned mult8) {
    __shared__ int cntlo[BINSMAX], cnthi[BINSMAX];
    __shared__ int tot[512];
    __shared__ int lcur[BINSMAX];
    int tid = threadIdx.x;
    int g = blockIdx.x;
    int s = g & 1, b = g >> 1;
    if (b >= nb) return;
    int bins = odd ? (8 << rsh) : (1 << rsh);      // <= 512
    int beg = boffs[b], end = boffs[b + 1];
    int len = end - beg;
    int mid = beg + (len >> 1);
    if (tid < bins) { cntlo[tid] = 0; cnthi[tid] = 0; }
    __syncthreads();
    for (int i = beg + tid; i < end; i += 512) {
        uint2 e = e1[i];
        int lrow = (int)(e.x >> 16);
        int bin = odd ? (lrow * 8 + seg8(e.x & 0xFFFFu, mult8)) : lrow;
        atomicAdd((i < mid) ? &cntlo[bin] : &cnthi[bin], 1);
    }
    __syncthreads();
    int lo = 0, own = 0;
    if (tid < bins) { lo = cntlo[tid]; own = lo + cnthi[tid]; }
    tot[tid] = own;
    __syncthreads();
    for (int off = 1; off < 512; off <<= 1) {
        int t = (tid >= off) ? tot[tid - off] : 0;
        __syncthreads();
        tot[tid] += t;
        __syncthreads();
    }
    if (tid < bins) {
        int fineoff = tot[tid] - own;              // exclusive within bucket
        lcur[tid] = beg + fineoff + (s ? lo : 0);
        if (s == 0) {
            if (!odd) {
                int row = (b << rsh) + tid;
                if (row < nrows) offs[row] = beg + fineoff;
            } else {
                int row = (b << rsh) + (tid >> 3);
                if (row < nrows) offs[(row << 3) + (tid & 7)] = beg + fineoff;
            }
        }
    }
    __syncthreads();
    int lo_i = s ? mid : beg;
    int hi_i = s ? end : mid;
    for (int i = lo_i + tid; i < hi_i; i += 512) {
        uint2 e = e1[i];
        int lrow = (int)(e.x >> 16);
        int bin = odd ? (lrow * 8 + seg8(e.x & 0xFFFFu, mult8)) : lrow;
        int slot = atomicAdd(&lcur[bin], 1);
        e2[slot] = make_uint2(e.x & 0xFFFFu, e.y);
    }
}

// ---------------- gather core (r8 form - L2-BW-pinned, do not touch) --------
__device__ __forceinline__ void chunk_accum(
        float4& acc, uint2 e, int n, const float* __restrict__ xq, int q) {
    int   c0 = __shfl((int)e.x, q);
    float v0 = __uint_as_float(__shfl((int)e.y, q));
    int   c1 = __shfl((int)e.x, 4 + q);
    float v1 = __uint_as_float(__shfl((int)e.y, 4 + q));
    float4 x0 = *(const float4*)(xq + (((size_t)c0) << 6));
    float4 x1 = *(const float4*)(xq + (((size_t)c1) << 6));
    for (int j = 8; j < n; j += 8) {
        int   nc0 = __shfl((int)e.x, j + q);
        float nv0 = __uint_as_float(__shfl((int)e.y, j + q));
        int   nc1 = __shfl((int)e.x, j + 4 + q);
        float nv1 = __uint_as_float(__shfl((int)e.y, j + 4 + q));
        float4 nx0 = *(const float4*)(xq + (((size_t)nc0) << 6));
        float4 nx1 = *(const float4*)(xq + (((size_t)nc1) << 6));
        acc.x += v0 * x0.x; acc.y += v0 * x0.y;
        acc.z += v0 * x0.z; acc.w += v0 * x0.w;
        acc.x += v1 * x1.x; acc.y += v1 * x1.y;
        acc.z += v1 * x1.z; acc.w += v1 * x1.w;
        v0 = nv0; v1 = nv1; x0 = nx0; x1 = nx1;
    }
    acc.x += v0 * x0.x; acc.y += v0 * x0.y;
    acc.z += v0 * x0.z; acc.w += v0 * x0.w;
    acc.x += v1 * x1.x; acc.y += v1 * x1.y;
    acc.z += v1 * x1.z; acc.w += v1 * x1.w;
}

__device__ __forceinline__ float4 gather_pre(
        uint2 e0, int beg, int end, const uint2* __restrict__ edges,
        const float* __restrict__ xq, int q, int lane) {
    float4 acc = make_float4(0.f, 0.f, 0.f, 0.f);
    int n0 = end - beg; if (n0 > 64) n0 = 64;
    chunk_accum(acc, e0, n0, xq, q);              // empty bin: e0 zero -> +0
    for (int base = beg + 64; base < end; base += 64) {
        int n = end - base; if (n > 64) n = 64;
        uint2 e = make_uint2(0u, 0u);
        if (lane < n) e = edges[base + lane];
        chunk_accum(acc, e, n, xq, q);
    }
    acc.x += __shfl_xor(acc.x, 16); acc.y += __shfl_xor(acc.y, 16);
    acc.z += __shfl_xor(acc.z, 16); acc.w += __shfl_xor(acc.w, 16);
    acc.x += __shfl_xor(acc.x, 32); acc.y += __shfl_xor(acc.y, 32);
    acc.z += __shfl_xor(acc.z, 32); acc.w += __shfl_xor(acc.w, 32);
    return acc;
}

// ---------------- C-even: per-row wave gather, 2 rows/wave pipelined --------
__global__ __launch_bounds__(256) void row_gather(
        const int* __restrict__ offs, const uint2* __restrict__ edges,
        const float* __restrict__ x, float* __restrict__ out, int nrows) {
    int wave = threadIdx.x >> 6, lane = threadIdx.x & 63;
    int q = lane >> 4, l16 = lane & 15;
    const float* xq = x + (l16 << 2);
    int rA = blockIdx.x * 8 + wave * 2;
    if (rA >= nrows) return;
    int rB = rA + 1;
    int begA = offs[rA], endA = offs[rA + 1];
    int begB = 0, endB = 0;
    if (rB < nrows) { begB = offs[rB]; endB = offs[rB + 1]; }
    int nA = endA - begA; if (nA > 64) nA = 64;
    int nB = endB - begB; if (nB > 64) nB = 64;
    uint2 eA = make_uint2(0u, 0u), eB = make_uint2(0u, 0u);
    if (lane < nA) eA = edges[begA + lane];
    if (lane < nB) eB = edges[begB + lane];     // in flight during A's compute
    float4 accA = gather_pre(eA, begA, endA, edges, xq, q, lane);
    if ((lane >> 4) == 0)
        *(float4*)(out + (((size_t)rA) << 6) + (l16 << 2)) = accA;
    if (rB < nrows) {
        float4 accB = gather_pre(eB, begB, endB, edges, xq, q, lane);
        if ((lane >> 4) == 0)
            *(float4*)(out + (((size_t)rB) << 6) + (l16 << 2)) = accB;
    }
}

// ---------------- C-odd: XCD-partitioned gather, 2 bins/wave pipelined ------
__global__ __launch_bounds__(256) void xcd_gather(
        const int* __restrict__ offs, const uint2* __restrict__ edges,
        const float* __restrict__ x, float* __restrict__ partial, int NP) {
    int g = blockIdx.x;
    int slot = g & 7;
    int t = g >> 3;
    int wave = threadIdx.x >> 6, lane = threadIdx.x & 63;
    int q = lane >> 4, l16 = lane & 15;
    const float* xq = x + (l16 << 2);
    int rA = t * 8 + wave * 2;
    if (rA >= NP) return;
    int rB = rA + 1;
    int binA = rA * 8 + slot;
    int begA = offs[binA], endA = offs[binA + 1];
    int begB = 0, endB = 0;
    if (rB < NP) { int binB = rB * 8 + slot; begB = offs[binB]; endB = offs[binB + 1]; }
    int nA = endA - begA; if (nA > 64) nA = 64;
    int nB = endB - begB; if (nB > 64) nB = 64;
    uint2 eA = make_uint2(0u, 0u), eB = make_uint2(0u, 0u);
    if (lane < nA) eA = edges[begA + lane];
    if (lane < nB) eB = edges[begB + lane];     // in flight during A's compute
    float4 accA = gather_pre(eA, begA, endA, edges, xq, q, lane);
    if ((lane >> 4) == 0)
        *(float4*)(partial + (size_t)slot * NP * 64 + (((size_t)rA) << 6) + (l16 << 2)) = accA;
    if (rB < NP) {
        float4 accB = gather_pre(eB, begB, endB, edges, xq, q, lane);
        if ((lane >> 4) == 0)
            *(float4*)(partial + (size_t)slot * NP * 64 + (((size_t)rB) << 6) + (l16 << 2)) = accB;
    }
}

__global__ __launch_bounds__(256) void reduce8(
        const float* __restrict__ partial, float* __restrict__ out, int n4) {
    int i = blockIdx.x * 256 + threadIdx.x;
    if (i < n4) {
        const float4* p = (const float4*)partial;
        float4 s = make_float4(0.f, 0.f, 0.f, 0.f);
        #pragma unroll
        for (int xx = 0; xx < 8; ++xx) {
            float4 v = p[(size_t)xx * n4 + i];
            s.x += v.x; s.y += v.y; s.z += v.z; s.w += v.w;
        }
        ((float4*)out)[i] = s;
    }
}

// ---------------- fallback: atomic scatter ----------------
__global__ void spmm_scatter_kernel(const int* __restrict__ rows, const int* __restrict__ cols,
                                    const float* __restrict__ vals,
                                    const float* __restrict__ s_emb, const float* __restrict__ p_emb,
                                    float* __restrict__ out_s, float* __restrict__ out_p, int nnz) {
    long long t = (long long)blockIdx.x * blockDim.x + threadIdx.x;
    int e = (int)(t >> 6);
    int d = (int)(t & 63);
    if (e >= nnz) return;
    int r = rows[e];
    int c = cols[e];
    float v = vals[e];
    atomicAdd(&out_s[(size_t)r * 64 + d], v * p_emb[(size_t)c * 64 + d]);
    atomicAdd(&out_p[(size_t)c * 64 + d], v * s_emb[(size_t)r * 64 + d]);
}

// ---------------- host ----------------
extern "C" void kernel_launch(void* const* d_in, const int* in_sizes, int n_in,
                              void* d_out, int out_size, void* d_ws, size_t ws_size,
                              hipStream_t stream) {
    const float* s_emb   = (const float*)d_in[0];
    const float* p_emb   = (const float*)d_in[1];
    const int*   a_rows  = (const int*)d_in[2];
    const int*   a_cols  = (const int*)d_in[3];
    const float* a_vals  = (const float*)d_in[4];
    const int*   ia_rows = (const int*)d_in[5];
    const int*   ia_cols = (const int*)d_in[6];
    const float* ia_vals = (const float*)d_in[7];

    const int NS  = in_sizes[0] / 64;
    const int NP  = in_sizes[1] / 64;
    const int nnz = in_sizes[2];
    const int NP8 = NP * 8;

    float* out = (float*)d_out;
    float* out_sc  = out;
    float* out_sic = out_sc  + (size_t)NS * 64;
    float* out_pc  = out_sic + (size_t)NS * 64;
    float* out_pic = out_pc  + (size_t)NP * 64;

    int rsh_s = 0; while ((((long long)NS + (1LL << rsh_s) - 1) >> rsh_s) > NBMAX) rsh_s++;
    int rsh_p = 0; while ((((long long)NP + (1LL << rsh_p) - 1) >> rsh_p) > NBMAX) rsh_p++;
    int nb_s = (NS + (1 << rsh_s) - 1) >> rsh_s;
    int nb_p = (NP + (1 << rsh_p) - 1) >> rsh_p;
    unsigned mult8 = (unsigned)((8ULL << 32) / (unsigned)NS);

    const size_t edges_bytes = (size_t)nnz * sizeof(uint2);
    const size_t offsE_bytes = (size_t)(NS + 1) * sizeof(int);
    const size_t offsO_bytes = (size_t)(NP8 + 1) * sizeof(int);
    const size_t fixed_bytes = offsE_bytes + offsO_bytes
                      + (size_t)(4 * NBMAX + 4 * (NBMAX + 1) + 4 * NBMAX) * sizeof(int) + 256;
    const size_t need  = 2 * edges_bytes + fixed_bytes;
    const size_t need3 = 3 * edges_bytes + fixed_bytes;
    const bool packable = (NS <= 0xFFFF) && (NP <= 0xFFFF) &&
                          ((1 << rsh_s) <= BINSMAX) && ((8 << rsh_p) <= BINSMAX) &&
                          (edges_bytes >= (size_t)NP8 * 64 * sizeof(float)) &&
                          ((NP * 64) % 4 == 0);

    if (ws_size < need || !packable) {
        hipMemsetAsync(d_out, 0, (size_t)out_size * sizeof(float), stream);
        const long long total = (long long)nnz * 64;
        const int grid = (int)((total + 255) / 256);
        spmm_scatter_kernel<<<grid, 256, 0, stream>>>(a_rows, a_cols, a_vals, s_emb, p_emb,
                                                      out_sc, out_pc, nnz);
        spmm_scatter_kernel<<<grid, 256, 0, stream>>>(ia_rows, ia_cols, ia_vals, s_emb, p_emb,
                                                      out_sic, out_pic, nnz);
        return;
    }

    const bool fused = (ws_size >= need3);

    char* w = (char*)d_ws;
    uint2* edges1 = (uint2*)w;  w += edges_bytes;
    uint2* edges2 = (uint2*)w;  w += edges_bytes;
    uint2* edges3 = nullptr;
    if (fused) { edges3 = (uint2*)w; w += edges_bytes; }
    int*   offsE  = (int*)w;    w += offsE_bytes;
    int*   offsO  = (int*)w;    w += offsO_bytes;
    int*   gcnt4  = (int*)w;    w += 4 * NBMAX * sizeof(int);
    int*   boffs4 = (int*)w;    w += 4 * (NBMAX + 1) * sizeof(int);
    int*   bcur4  = (int*)w;

    hipMemsetAsync(gcnt4, 0, 4 * NBMAX * sizeof(int), stream);
    // dirs: 0 = a by row, 1 = a by col, 2 = ia by row, 3 = ia by col
    hist_all<<<1024, 256, 0, stream>>>(a_rows, a_cols, ia_rows, ia_cols,
                                       gcnt4, nnz, rsh_s, rsh_p);
    scan_all<<<4, 256, 0, stream>>>(gcnt4, boffs4, bcur4, nb_s, nb_p, nnz,
                                    offsE, offsO, NS, NP8);

    if (fused) {
        const int ntiles2 = (nnz + FTILE - 1) / FTILE;
        struct Mat { const int* r; const int* c; const float* v;
                     float* oe; float* oo; int de, dodd; };
        Mat mats[2] = {
            { a_rows,  a_cols,  a_vals,  out_sc,  out_pc,  0, 1 },
            { ia_rows, ia_cols, ia_vals, out_sic, out_pic, 2, 3 },
        };
        for (int m = 0; m < 2; ++m) {
            const Mat& M = mats[m];
            // one pass over (rows,cols,vals): even buckets -> e1, odd -> e3
            staged_scatter2<<<ntiles2, 256, 0, stream>>>(M.r, M.c, M.v,
                    bcur4 + M.de * NBMAX, bcur4 + M.dodd * NBMAX,
                    edges1, edges3, nnz, rsh_s, rsh_p);
            row_sort2<<<nb_s * 2, 512, 0, stream>>>(edges1, edges2,
                    boffs4 + M.de * (NBMAX + 1), offsE, 0, nb_s, rsh_s, NS, mult8);
            row_gather<<<(NS + 7) / 8, 256, 0, stream>>>(offsE, edges2, p_emb, M.oe, NS);
            row_sort2<<<nb_p * 2, 512, 0, stream>>>(edges3, edges1,
                    boffs4 + M.dodd * (NBMAX + 1), offsO, 1, nb_p, rsh_p, NP, mult8);
            xcd_gather<<<8 * ((NP + 7) / 8), 256, 0, stream>>>(offsO, edges1,
                    s_emb, (float*)edges3, NP);
            reduce8<<<(NP * 64 / 4 + 255) / 256, 256, 0, stream>>>((float*)edges3,
                    M.oo, NP * 64 / 4);
        }
        return;
    }

    // ---- non-fused (ws-tight) path: r8 structure ----
    float* partial = (float*)edges1;
    const int ntiles = (nnz + TILE - 1) / TILE;
    struct Dir { const int* key; const int* other; const float* vals;
                 float* out; int odd; };
    Dir dirs[4] = {
        { a_rows,  a_cols,  a_vals,  out_sc,  0 },
        { a_cols,  a_rows,  a_vals,  out_pc,  1 },
        { ia_rows, ia_cols, ia_vals, out_sic, 0 },
        { ia_cols, ia_rows, ia_vals, out_pic, 1 },
    };
    for (int t = 0; t < 4; ++t) {
        const Dir& D = dirs[t];
        if (!D.odd) {
            staged_scatter<<<ntiles, 256, 0, stream>>>(D.key, D.other, D.vals,
                                                       bcur4 + t * NBMAX, edges1, nnz, rsh_s);
            row_sort1<<<nb_s, 512, 0, stream>>>(edges1, edges2,
                                                boffs4 + t * (NBMAX + 1), offsE,
                                                0, nb_s, rsh_s, NS, mult8);
            row_gather<<<(NS + 7) / 8, 256, 0, stream>>>(offsE, edges2, p_emb, D.out, NS);
        } else {
            staged_scatter<<<ntiles, 256, 0, stream>>>(D.key, D.other, D.vals,
                                                       bcur4 + t * NBMAX, edges1, nnz, rsh_p);
            row_sort1<<<nb_p, 512, 0, stream>>>(edges1, edges2,
                                                boffs4 + t * (NBMAX + 1), offsO,
                                                1, nb_p, rsh_p, NP, mult8);
            xcd_gather<<<8 * ((NP + 7) / 8), 256, 0, stream>>>(offsO, edges2,
                                                               s_emb, partial, NP);
            reduce8<<<(NP * 64 / 4 + 255) / 256, 256, 0, stream>>>(partial, D.out, NP * 64 / 4);
        }
    }
}

// Round 14
// 536.882 us; speedup vs baseline: 1.8074x; 1.0796x over previous
//
#include <hip/hip_runtime.h>
#include <hip/hip_bf16.h>

#define NBMAX 256   // coarse buckets per direction
#define TILE  4096  // edges per staged-scatter tile (per-dir fallback)
#define KPT   16    // TILE / 256
#define FTILE 2048  // edges per fused-scatter tile
#define FKPT  8     // FTILE / 256
#define BINSMAX 512 // max fine bins per bucket

// seg(student) in [0,8): near-uniform 8-way split via magic multiply
__device__ __forceinline__ int seg8(unsigned r, unsigned mult8) {
    return (int)__umulhi(r, mult8);
}

// ---------------- A1: coarse histogram, all 4 dirs (LDS-privatized) ---------
__global__ __launch_bounds__(256) void hist_all(
        const int* __restrict__ k0, const int* __restrict__ k1,
        const int* __restrict__ k2, const int* __restrict__ k3,
        int* __restrict__ gcnt4, int nnz, int rsh_s, int rsh_p) {
    __shared__ int h[NBMAX];
    int dir = blockIdx.x & 3;
    const int* key = (dir == 0) ? k0 : (dir == 1) ? k1 : (dir == 2) ? k2 : k3;
    int rsh = (dir & 1) ? rsh_p : rsh_s;
    h[threadIdx.x] = 0;
    __syncthreads();
    int ch = blockIdx.x >> 2, nch = gridDim.x >> 2;
    int nnz4 = nnz >> 2;
    for (int i = ch * 256 + threadIdx.x; i < nnz4; i += nch * 256) {
        int4 k4 = ((const int4*)key)[i];
        atomicAdd(&h[k4.x >> rsh], 1);
        atomicAdd(&h[k4.y >> rsh], 1);
        atomicAdd(&h[k4.z >> rsh], 1);
        atomicAdd(&h[k4.w >> rsh], 1);
    }
    if (ch == 0) {
        for (int i = (nnz4 << 2) + threadIdx.x; i < nnz; i += 256)
            atomicAdd(&h[key[i] >> rsh], 1);
    }
    __syncthreads();
    int v = h[threadIdx.x];
    if (v) atomicAdd(&gcnt4[dir * NBMAX + threadIdx.x], v);
}

// ---------------- A2: bucket offsets for all 4 dirs (4 blocks) --------------
__global__ __launch_bounds__(256) void scan_all(
        const int* __restrict__ gcnt4, int* __restrict__ boffs4,
        int* __restrict__ bcur4, int nb_s, int nb_p, int nnz,
        int* __restrict__ offsE, int* __restrict__ offsO, int NS, int NP8) {
    __shared__ int tmp[NBMAX];
    int dir = blockIdx.x, tid = threadIdx.x;
    int nb = (dir & 1) ? nb_p : nb_s;
    int v = (tid < nb) ? gcnt4[dir * NBMAX + tid] : 0;
    tmp[tid] = v;
    __syncthreads();
    for (int off = 1; off < NBMAX; off <<= 1) {
        int t = (tid >= off) ? tmp[tid - off] : 0;
        __syncthreads();
        tmp[tid] += t;
        __syncthreads();
    }
    if (tid < nb) {
        int e = tmp[tid] - v;
        boffs4[dir * (NBMAX + 1) + tid] = e;
        bcur4[dir * NBMAX + tid] = e;
    }
    if (tid == 0) boffs4[dir * (NBMAX + 1) + nb] = nnz;
    if (dir == 0 && tid == 0) { offsE[NS] = nnz; offsO[NP8] = nnz; }
}

// ---------------- A3a: per-dir staged scatter (fallback when ws is tight) ---
__global__ __launch_bounds__(256) void staged_scatter(
        const int* __restrict__ key, const int* __restrict__ other,
        const float* __restrict__ vals, int* __restrict__ cursor,
        uint2* __restrict__ edges, int nnz, int rsh) {
    __shared__ int lhist[NBMAX], lofs[NBMAX], lbase[NBMAX];
    __shared__ uint2 stage[TILE];
    __shared__ int   sslot[TILE];
    int tid = threadIdx.x;
    int lmask = (1 << rsh) - 1;
    int ntiles = (nnz + TILE - 1) / TILE;
    for (int tile = blockIdx.x; tile < ntiles; tile += gridDim.x) {
        int tbeg = tile * TILE;
        int n = nnz - tbeg; if (n > TILE) n = TILE;
        lhist[tid] = 0;
        __syncthreads();
        int myb[KPT], myr[KPT]; unsigned myo[KPT]; float myv[KPT];
        #pragma unroll
        for (int g = 0; g < 4; ++g) {
            int s = g * 1024 + tid * 4;
            if (s + 4 <= n) {
                int i = tbeg + s;
                int4   k4 = *(const int4*)(key + i);
                int4   o4 = *(const int4*)(other + i);
                float4 v4 = *(const float4*)(vals + i);
                int   kk[4] = {k4.x, k4.y, k4.z, k4.w};
                int   oo[4] = {o4.x, o4.y, o4.z, o4.w};
                float vv[4] = {v4.x, v4.y, v4.z, v4.w};
                #pragma unroll
                for (int k = 0; k < 4; ++k) {
                    int m = g * 4 + k;
                    myb[m] = kk[k] >> rsh;
                    myo[m] = (unsigned)oo[k] | ((unsigned)(kk[k] & lmask) << 16);
                    myv[m] = vv[k];
                    myr[m] = atomicAdd(&lhist[myb[m]], 1);
                }
            } else {
                #pragma unroll
                for (int k = 0; k < 4; ++k) {
                    int m = g * 4 + k;
                    int s2 = s + k;
                    if (s2 < n) {
                        int i = tbeg + s2;
                        int ky = key[i];
                        myb[m] = ky >> rsh;
                        myo[m] = (unsigned)other[i] | ((unsigned)(ky & lmask) << 16);
                        myv[m] = vals[i];
                        myr[m] = atomicAdd(&lhist[myb[m]], 1);
                    } else myb[m] = -1;
                }
            }
        }
        __syncthreads();
        int h = lhist[tid];
        lofs[tid] = h;
        __syncthreads();
        for (int off = 1; off < NBMAX; off <<= 1) {
            int t = (tid >= off) ? lofs[tid - off] : 0;
            __syncthreads();
            lofs[tid] += t;
            __syncthreads();
        }
        lofs[tid] -= h;
        if (h > 0) lbase[tid] = atomicAdd(&cursor[tid], h);
        __syncthreads();
        #pragma unroll
        for (int k = 0; k < KPT; ++k) {
            if (myb[k] >= 0) {
                int ls = lofs[myb[k]] + myr[k];
                stage[ls] = make_uint2(myo[k], __float_as_uint(myv[k]));
                sslot[ls] = lbase[myb[k]] + myr[k];
            }
        }
        __syncthreads();
        #pragma unroll
        for (int k = 0; k < KPT; ++k) {
            int s = k * 256 + tid;
            if (s < n) edges[sslot[s]] = stage[s];
        }
        __syncthreads();
    }
}

// ---------------- A3b: FUSED scatter (r10 form) + optional merged reduce ----
// r10-proven body (61.7us). Blocks [0,nred) instead run the reduce8 of the
// PREVIOUS matrix's odd partial (data-independent: partial lives in edges2,
// scatter writes e1/e3) - free overlap, one less serialized launch.
__global__ __launch_bounds__(256) void staged_scatter2(
        const int* __restrict__ krow, const int* __restrict__ kcol,
        const float* __restrict__ vals,
        int* __restrict__ curE, int* __restrict__ curO,
        uint2* __restrict__ edgesE, uint2* __restrict__ edgesO,
        int nnz, int rsh_e, int rsh_o, int sgrid,
        const float* __restrict__ rpart, float* __restrict__ rout, int n4red) {
    __shared__ int lhistE[NBMAX], lofsE[NBMAX], lbaseE[NBMAX];
    __shared__ int lhistO[NBMAX], lofsO[NBMAX], lbaseO[NBMAX];
    __shared__ uint2 stageE[FTILE], stageO[FTILE];
    __shared__ int   sslotE[FTILE], sslotO[FTILE];
    int tid = threadIdx.x;
    int nred = (n4red + 255) >> 8;
    if ((int)blockIdx.x < nred) {                  // merged reduce8 (prev mat)
        int i = blockIdx.x * 256 + tid;
        if (i < n4red) {
            const float4* p = (const float4*)rpart;
            float4 s = make_float4(0.f, 0.f, 0.f, 0.f);
            #pragma unroll
            for (int xx = 0; xx < 8; ++xx) {
                float4 v = p[(size_t)xx * n4red + i];
                s.x += v.x; s.y += v.y; s.z += v.z; s.w += v.w;
            }
            ((float4*)rout)[i] = s;
        }
        return;
    }
    int sb = blockIdx.x - nred;
    int lmE = (1 << rsh_e) - 1, lmO = (1 << rsh_o) - 1;
    int ntiles = (nnz + FTILE - 1) / FTILE;
    for (int tile = sb; tile < ntiles; tile += sgrid) {
        int tbeg = tile * FTILE;
        int n = nnz - tbeg; if (n > FTILE) n = FTILE;
        lhistE[tid] = 0; lhistO[tid] = 0;
        __syncthreads();
        int mbE[FKPT], mrE[FKPT]; unsigned moE[FKPT];
        int mbO[FKPT], mrO[FKPT]; unsigned moO[FKPT];
        float mv[FKPT];
        #pragma unroll
        for (int g = 0; g < 2; ++g) {
            int s = g * 1024 + tid * 4;           // 4 consecutive edges/thread
            if (s + 4 <= n) {
                int i = tbeg + s;
                int4   r4 = *(const int4*)(krow + i);
                int4   c4 = *(const int4*)(kcol + i);
                float4 v4 = *(const float4*)(vals + i);
                int   rr[4] = {r4.x, r4.y, r4.z, r4.w};
                int   cc[4] = {c4.x, c4.y, c4.z, c4.w};
                float vv[4] = {v4.x, v4.y, v4.z, v4.w};
                #pragma unroll
                for (int k = 0; k < 4; ++k) {
                    int m = g * 4 + k;
                    mv[m]  = vv[k];
                    mbE[m] = rr[k] >> rsh_e;
                    moE[m] = (unsigned)cc[k] | ((unsigned)(rr[k] & lmE) << 16);
                    mrE[m] = atomicAdd(&lhistE[mbE[m]], 1);
                    mbO[m] = cc[k] >> rsh_o;
                    moO[m] = (unsigned)rr[k] | ((unsigned)(cc[k] & lmO) << 16);
                    mrO[m] = atomicAdd(&lhistO[mbO[m]], 1);
                }
            } else {
                #pragma unroll
                for (int k = 0; k < 4; ++k) {
                    int m = g * 4 + k;
                    int s2 = s + k;
                    if (s2 < n) {
                        int i = tbeg + s2;
                        int r = krow[i], c = kcol[i];
                        mv[m]  = vals[i];
                        mbE[m] = r >> rsh_e;
                        moE[m] = (unsigned)c | ((unsigned)(r & lmE) << 16);
                        mrE[m] = atomicAdd(&lhistE[mbE[m]], 1);
                        mbO[m] = c >> rsh_o;
                        moO[m] = (unsigned)r | ((unsigned)(c & lmO) << 16);
                        mrO[m] = atomicAdd(&lhistO[mbO[m]], 1);
                    } else { mbE[m] = -1; mbO[m] = -1; }
                }
            }
        }
        __syncthreads();
        int hE = lhistE[tid], hO = lhistO[tid];
        lofsE[tid] = hE; lofsO[tid] = hO;
        __syncthreads();
        for (int off = 1; off < NBMAX; off <<= 1) {
            int tE = (tid >= off) ? lofsE[tid - off] : 0;
            int tO = (tid >= off) ? lofsO[tid - off] : 0;
            __syncthreads();
            lofsE[tid] += tE; lofsO[tid] += tO;
            __syncthreads();
        }
        lofsE[tid] -= hE; lofsO[tid] -= hO;
        if (hE > 0) lbaseE[tid] = atomicAdd(&curE[tid], hE);
        if (hO > 0) lbaseO[tid] = atomicAdd(&curO[tid], hO);
        __syncthreads();
        #pragma unroll
        for (int k = 0; k < FKPT; ++k) {
            if (mbE[k] >= 0) {
                int lsE = lofsE[mbE[k]] + mrE[k];
                stageE[lsE] = make_uint2(moE[k], __float_as_uint(mv[k]));
                sslotE[lsE] = lbaseE[mbE[k]] + mrE[k];
                int lsO = lofsO[mbO[k]] + mrO[k];
                stageO[lsO] = make_uint2(moO[k], __float_as_uint(mv[k]));
                sslotO[lsO] = lbaseO[mbO[k]] + mrO[k];
            }
        }
        __syncthreads();
        #pragma unroll
        for (int k = 0; k < FKPT; ++k) {
            int s = k * 256 + tid;
            if (s < n) {
                edgesE[sslotE[s]] = stageE[s];
                edgesO[sslotO[s]] = stageO[s];
            }
        }
        __syncthreads();
    }
}

// ---------------- B: one block per bucket, 2-pass fine sort (r8-proven) -----
__global__ __launch_bounds__(512) void row_sort1(
        const uint2* __restrict__ e1, uint2* __restrict__ e2,
        const int* __restrict__ boffs, int* __restrict__ offs,
        int odd, int nb, int rsh, int nrows, unsigned mult8) {
    __shared__ int cnt[BINSMAX];                   // counts, then cursors
    __shared__ int tot[512];
    int tid = threadIdx.x;
    int b = blockIdx.x;
    if (b >= nb) return;
    int bins = odd ? (8 << rsh) : (1 << rsh);      // <= 512
    int beg = boffs[b], end = boffs[b + 1];
    if (tid < bins) cnt[tid] = 0;
    __syncthreads();
    for (int i = beg + tid; i < end; i += 512) {
        uint2 e = e1[i];
        int lrow = (int)(e.x >> 16);
        int bin = odd ? (lrow * 8 + seg8(e.x & 0xFFFFu, mult8)) : lrow;
        atomicAdd(&cnt[bin], 1);
    }
    __syncthreads();
    int own = (tid < bins) ? cnt[tid] : 0;
    tot[tid] = own;
    __syncthreads();
    for (int off = 1; off < 512; off <<= 1) {
        int t = (tid >= off) ? tot[tid - off] : 0;
        __syncthreads();
        tot[tid] += t;
        __syncthreads();
    }
    if (tid < bins) {
        int fineoff = tot[tid] - own;              // exclusive within bucket
        cnt[tid] = beg + fineoff;                  // becomes cursor
        if (!odd) {
            int row = (b << rsh) + tid;
            if (row < nrows) offs[row] = beg + fineoff;
        } else {
            int row = (b << rsh) + (tid >> 3);
            if (row < nrows) offs[(row << 3) + (tid & 7)] = beg + fineoff;
        }
    }
    __syncthreads();
    for (int i = beg + tid; i < end; i += 512) {
        uint2 e = e1[i];
        int lrow = (int)(e.x >> 16);
        int bin = odd ? (lrow * 8 + seg8(e.x & 0xFFFFu, mult8)) : lrow;
        int slot = atomicAdd(&cnt[bin], 1);
        e2[slot] = make_uint2(e.x & 0xFFFFu, e.y);
    }
}

// ---------------- gather core (r8 form - L2-BW-pinned, do not touch) --------
__device__ __forceinline__ void chunk_accum(
        float4& acc, uint2 e, int n, const float* __restrict__ xq, int q) {
    int   c0 = __shfl((int)e.x, q);
    float v0 = __uint_as_float(__shfl((int)e.y, q));
    int   c1 = __shfl((int)e.x, 4 + q);
    float v1 = __uint_as_float(__shfl((int)e.y, 4 + q));
    float4 x0 = *(const float4*)(xq + (((size_t)c0) << 6));
    float4 x1 = *(const float4*)(xq + (((size_t)c1) << 6));
    for (int j = 8; j < n; j += 8) {
        int   nc0 = __shfl((int)e.x, j + q);
        float nv0 = __uint_as_float(__shfl((int)e.y, j + q));
        int   nc1 = __shfl((int)e.x, j + 4 + q);
        float nv1 = __uint_as_float(__shfl((int)e.y, j + 4 + q));
        float4 nx0 = *(const float4*)(xq + (((size_t)nc0) << 6));
        float4 nx1 = *(const float4*)(xq + (((size_t)nc1) << 6));
        acc.x += v0 * x0.x; acc.y += v0 * x0.y;
        acc.z += v0 * x0.z; acc.w += v0 * x0.w;
        acc.x += v1 * x1.x; acc.y += v1 * x1.y;
        acc.z += v1 * x1.z; acc.w += v1 * x1.w;
        v0 = nv0; v1 = nv1; x0 = nx0; x1 = nx1;
    }
    acc.x += v0 * x0.x; acc.y += v0 * x0.y;
    acc.z += v0 * x0.z; acc.w += v0 * x0.w;
    acc.x += v1 * x1.x; acc.y += v1 * x1.y;
    acc.z += v1 * x1.z; acc.w += v1 * x1.w;
}

__device__ __forceinline__ float4 gather_pre(
        uint2 e0, int beg, int end, const uint2* __restrict__ edges,
        const float* __restrict__ xq, int q, int lane) {
    float4 acc = make_float4(0.f, 0.f, 0.f, 0.f);
    int n0 = end - beg; if (n0 > 64) n0 = 64;
    chunk_accum(acc, e0, n0, xq, q);              // empty bin: e0 zero -> +0
    for (int base = beg + 64; base < end; base += 64) {
        int n = end - base; if (n > 64) n = 64;
        uint2 e = make_uint2(0u, 0u);
        if (lane < n) e = edges[base + lane];
        chunk_accum(acc, e, n, xq, q);
    }
    acc.x += __shfl_xor(acc.x, 16); acc.y += __shfl_xor(acc.y, 16);
    acc.z += __shfl_xor(acc.z, 16); acc.w += __shfl_xor(acc.w, 16);
    acc.x += __shfl_xor(acc.x, 32); acc.y += __shfl_xor(acc.y, 32);
    acc.z += __shfl_xor(acc.z, 32); acc.w += __shfl_xor(acc.w, 32);
    return acc;
}

// ---------------- device body: even gather for one (block,wave) -------------
__device__ __forceinline__ void gatherE_body(
        int rA, const int* __restrict__ offs, const uint2* __restrict__ edges,
        const float* __restrict__ x, float* __restrict__ out, int nrows,
        int lane) {
    int q = lane >> 4, l16 = lane & 15;
    const float* xq = x + (l16 << 2);
    if (rA >= nrows) return;
    int rB = rA + 1;
    int begA = offs[rA], endA = offs[rA + 1];
    int begB = 0, endB = 0;
    if (rB < nrows) { begB = offs[rB]; endB = offs[rB + 1]; }
    int nA = endA - begA; if (nA > 64) nA = 64;
    int nB = endB - begB; if (nB > 64) nB = 64;
    uint2 eA = make_uint2(0u, 0u), eB = make_uint2(0u, 0u);
    if (lane < nA) eA = edges[begA + lane];
    if (lane < nB) eB = edges[begB + lane];     // in flight during A's compute
    float4 accA = gather_pre(eA, begA, endA, edges, xq, q, lane);
    if ((lane >> 4) == 0)
        *(float4*)(out + (((size_t)rA) << 6) + (l16 << 2)) = accA;
    if (rB < nrows) {
        float4 accB = gather_pre(eB, begB, endB, edges, xq, q, lane);
        if ((lane >> 4) == 0)
            *(float4*)(out + (((size_t)rB) << 6) + (l16 << 2)) = accB;
    }
}

// ---------------- C-even standalone (fallback path) ----------------
__global__ __launch_bounds__(256) void row_gather(
        const int* __restrict__ offs, const uint2* __restrict__ edges,
        const float* __restrict__ x, float* __restrict__ out, int nrows) {
    int wave = threadIdx.x >> 6, lane = threadIdx.x & 63;
    gatherE_body(blockIdx.x * 8 + wave * 2, offs, edges, x, out, nrows, lane);
}

// ---------------- MERGED: sortO (blocks [0,nb_p)) + gatherE (rest) ----------
// Data-independent (gatherE: e2/p_emb -> out; sortO: e3 -> e1) - one launch
// co-runs them. Sort blocks FIRST so they dispatch immediately; gather's
// thousands of blocks fill the rest of the machine. Gather at 512 threads =
// 8 waves x 2 rows = 16 rows/block.
__global__ __launch_bounds__(512) void gatherE_sortO(
        const int* __restrict__ offsE_, const uint2* __restrict__ e2g,
        const float* __restrict__ xg, float* __restrict__ outg, int nrows,
        const uint2* __restrict__ e1s, uint2* __restrict__ e2s,
        const int* __restrict__ boffsS, int* __restrict__ offsS,
        int nb, int rsh, int nrowsS, unsigned mult8) {
    int tid = threadIdx.x;
    if ((int)blockIdx.x >= nb) {                   // ---- gather part ----
        int gb = blockIdx.x - nb;
        int wave = tid >> 6, lane = tid & 63;
        gatherE_body(gb * 16 + wave * 2, offsE_, e2g, xg, outg, nrows, lane);
        return;
    }
    // ---- sortO part (row_sort1 body, odd=1) ----
    __shared__ int cnt[BINSMAX];
    __shared__ int tot[512];
    int b = blockIdx.x;
    int bins = 8 << rsh;                           // <= 512
    int beg = boffsS[b], end = boffsS[b + 1];
    if (tid < bins) cnt[tid] = 0;
    __syncthreads();
    for (int i = beg + tid; i < end; i += 512) {
        uint2 e = e1s[i];
        int lrow = (int)(e.x >> 16);
        int bin = lrow * 8 + seg8(e.x & 0xFFFFu, mult8);
        atomicAdd(&cnt[bin], 1);
    }
    __syncthreads();
    int own = (tid < bins) ? cnt[tid] : 0;
    tot[tid] = own;
    __syncthreads();
    for (int off = 1; off < 512; off <<= 1) {
        int t = (tid >= off) ? tot[tid - off] : 0;
        __syncthreads();
        tot[tid] += t;
        __syncthreads();
    }
    if (tid < bins) {
        int fineoff = tot[tid] - own;
        cnt[tid] = beg + fineoff;
        int row = (b << rsh) + (tid >> 3);
        if (row < nrowsS) offsS[(row << 3) + (tid & 7)] = beg + fineoff;
    }
    __syncthreads();
    for (int i = beg + tid; i < end; i += 512) {
        uint2 e = e1s[i];
        int lrow = (int)(e.x >> 16);
        int bin = lrow * 8 + seg8(e.x & 0xFFFFu, mult8);
        int slot = atomicAdd(&cnt[bin], 1);
        e2s[slot] = make_uint2(e.x & 0xFFFFu, e.y);
    }
}

// ---------------- C-odd: XCD-partitioned gather, 2 bins/wave pipelined ------
__global__ __launch_bounds__(256) void xcd_gather(
        const int* __restrict__ offs, const uint2* __restrict__ edges,
        const float* __restrict__ x, float* __restrict__ partial, int NP) {
    int g = blockIdx.x;
    int slot = g & 7;
    int t = g >> 3;
    int wave = threadIdx.x >> 6, lane = threadIdx.x & 63;
    int q = lane >> 4, l16 = lane & 15;
    const float* xq = x + (l16 << 2);
    int rA = t * 8 + wave * 2;
    if (rA >= NP) return;
    int rB = rA + 1;
    int binA = rA * 8 + slot;
    int begA = offs[binA], endA = offs[binA + 1];
    int begB = 0, endB = 0;
    if (rB < NP) { int binB = rB * 8 + slot; begB = offs[binB]; endB = offs[binB + 1]; }
    int nA = endA - begA; if (nA > 64) nA = 64;
    int nB = endB - begB; if (nB > 64) nB = 64;
    uint2 eA = make_uint2(0u, 0u), eB = make_uint2(0u, 0u);
    if (lane < nA) eA = edges[begA + lane];
    if (lane < nB) eB = edges[begB + lane];     // in flight during A's compute
    float4 accA = gather_pre(eA, begA, endA, edges, xq, q, lane);
    if ((lane >> 4) == 0)
        *(float4*)(partial + (size_t)slot * NP * 64 + (((size_t)rA) << 6) + (l16 << 2)) = accA;
    if (rB < NP) {
        float4 accB = gather_pre(eB, begB, endB, edges, xq, q, lane);
        if ((lane >> 4) == 0)
            *(float4*)(partial + (size_t)slot * NP * 64 + (((size_t)rB) << 6) + (l16 << 2)) = accB;
    }
}

__global__ __launch_bounds__(256) void reduce8(
        const float* __restrict__ partial, float* __restrict__ out, int n4) {
    int i = blockIdx.x * 256 + threadIdx.x;
    if (i < n4) {
        const float4* p = (const float4*)partial;
        float4 s = make_float4(0.f, 0.f, 0.f, 0.f);
        #pragma unroll
        for (int xx = 0; xx < 8; ++xx) {
            float4 v = p[(size_t)xx * n4 + i];
            s.x += v.x; s.y += v.y; s.z += v.z; s.w += v.w;
        }
        ((float4*)out)[i] = s;
    }
}

// ---------------- fallback: atomic scatter ----------------
__global__ void spmm_scatter_kernel(const int* __restrict__ rows, const int* __restrict__ cols,
                                    const float* __restrict__ vals,
                                    const float* __restrict__ s_emb, const float* __restrict__ p_emb,
                                    float* __restrict__ out_s, float* __restrict__ out_p, int nnz) {
    long long t = (long long)blockIdx.x * blockDim.x + threadIdx.x;
    int e = (int)(t >> 6);
    int d = (int)(t & 63);
    if (e >= nnz) return;
    int r = rows[e];
    int c = cols[e];
    float v = vals[e];
    atomicAdd(&out_s[(size_t)r * 64 + d], v * p_emb[(size_t)c * 64 + d]);
    atomicAdd(&out_p[(size_t)c * 64 + d], v * s_emb[(size_t)r * 64 + d]);
}

// ---------------- host ----------------
extern "C" void kernel_launch(void* const* d_in, const int* in_sizes, int n_in,
                              void* d_out, int out_size, void* d_ws, size_t ws_size,
                              hipStream_t stream) {
    const float* s_emb   = (const float*)d_in[0];
    const float* p_emb   = (const float*)d_in[1];
    const int*   a_rows  = (const int*)d_in[2];
    const int*   a_cols  = (const int*)d_in[3];
    const float* a_vals  = (const float*)d_in[4];
    const int*   ia_rows = (const int*)d_in[5];
    const int*   ia_cols = (const int*)d_in[6];
    const float* ia_vals = (const float*)d_in[7];

    const int NS  = in_sizes[0] / 64;
    const int NP  = in_sizes[1] / 64;
    const int nnz = in_sizes[2];
    const int NP8 = NP * 8;

    float* out = (float*)d_out;
    float* out_sc  = out;
    float* out_sic = out_sc  + (size_t)NS * 64;
    float* out_pc  = out_sic + (size_t)NS * 64;
    float* out_pic = out_pc  + (size_t)NP * 64;

    int rsh_s = 0; while ((((long long)NS + (1LL << rsh_s) - 1) >> rsh_s) > NBMAX) rsh_s++;
    int rsh_p = 0; while ((((long long)NP + (1LL << rsh_p) - 1) >> rsh_p) > NBMAX) rsh_p++;
    int nb_s = (NS + (1 << rsh_s) - 1) >> rsh_s;
    int nb_p = (NP + (1 << rsh_p) - 1) >> rsh_p;
    unsigned mult8 = (unsigned)((8ULL << 32) / (unsigned)NS);

    const size_t edges_bytes = (size_t)nnz * sizeof(uint2);
    const size_t offsE_bytes = (size_t)(NS + 1) * sizeof(int);
    const size_t offsO_bytes = (size_t)(NP8 + 1) * sizeof(int);
    const size_t fixed_bytes = offsE_bytes + offsO_bytes
                      + (size_t)(4 * NBMAX + 4 * (NBMAX + 1) + 4 * NBMAX) * sizeof(int) + 256;
    const size_t need  = 2 * edges_bytes + fixed_bytes;
    const size_t need3 = 3 * edges_bytes + fixed_bytes;
    const bool packable = (NS <= 0xFFFF) && (NP <= 0xFFFF) &&
                          ((1 << rsh_s) <= BINSMAX) && ((8 << rsh_p) <= BINSMAX) &&
                          (edges_bytes >= (size_t)NP8 * 64 * sizeof(float)) &&
                          ((NP * 64) % 4 == 0);

    if (ws_size < need || !packable) {
        hipMemsetAsync(d_out, 0, (size_t)out_size * sizeof(float), stream);
        const long long total = (long long)nnz * 64;
        const int grid = (int)((total + 255) / 256);
        spmm_scatter_kernel<<<grid, 256, 0, stream>>>(a_rows, a_cols, a_vals, s_emb, p_emb,
                                                      out_sc, out_pc, nnz);
        spmm_scatter_kernel<<<grid, 256, 0, stream>>>(ia_rows, ia_cols, ia_vals, s_emb, p_emb,
                                                      out_sic, out_pic, nnz);
        return;
    }

    const bool fused = (ws_size >= need3);

    char* w = (char*)d_ws;
    uint2* edges1 = (uint2*)w;  w += edges_bytes;
    uint2* edges2 = (uint2*)w;  w += edges_bytes;
    uint2* edges3 = nullptr;
    if (fused) { edges3 = (uint2*)w; w += edges_bytes; }
    int*   offsE  = (int*)w;    w += offsE_bytes;
    int*   offsO  = (int*)w;    w += offsO_bytes;
    int*   gcnt4  = (int*)w;    w += 4 * NBMAX * sizeof(int);
    int*   boffs4 = (int*)w;    w += 4 * (NBMAX + 1) * sizeof(int);
    int*   bcur4  = (int*)w;

    hipMemsetAsync(gcnt4, 0, 4 * NBMAX * sizeof(int), stream);
    // dirs: 0 = a by row, 1 = a by col, 2 = ia by row, 3 = ia by col
    hist_all<<<1024, 256, 0, stream>>>(a_rows, a_cols, ia_rows, ia_cols,
                                       gcnt4, nnz, rsh_s, rsh_p);
    scan_all<<<4, 256, 0, stream>>>(gcnt4, boffs4, bcur4, nb_s, nb_p, nnz,
                                    offsE, offsO, NS, NP8);

    if (fused) {
        const int ntiles2 = (nnz + FTILE - 1) / FTILE;
        const int ggrid = (NS + 15) / 16;          // gather blocks (16 rows ea)
        const int n4red = NP * 64 / 4;
        const int nred  = (n4red + 255) / 256;
        struct Mat { const int* r; const int* c; const float* v;
                     float* oe; float* oo; int de, dodd; };
        Mat mats[2] = {
            { a_rows,  a_cols,  a_vals,  out_sc,  out_pc,  0, 1 },
            { ia_rows, ia_cols, ia_vals, out_sic, out_pic, 2, 3 },
        };
        for (int m = 0; m < 2; ++m) {
            const Mat& M = mats[m];
            // scatter (E->e1, O->e3); for m=1 also absorbs reduce8 of m0's
            // odd partial (in e2 - independent of e1/e3 writes)
            int red_n4 = (m == 1) ? n4red : 0;
            int red_blocks = (m == 1) ? nred : 0;
            staged_scatter2<<<ntiles2 + red_blocks, 256, 0, stream>>>(
                    M.r, M.c, M.v,
                    bcur4 + M.de * NBMAX, bcur4 + M.dodd * NBMAX,
                    edges1, edges3, nnz, rsh_s, rsh_p, ntiles2,
                    (const float*)edges2, mats[0].oo, red_n4);
            row_sort1<<<nb_s, 512, 0, stream>>>(edges1, edges2,
                    boffs4 + M.de * (NBMAX + 1), offsE, 0, nb_s, rsh_s, NS, mult8);
            // merged: sortO (e3->e1) first nb_p blocks + gatherE (e2) rest
            gatherE_sortO<<<nb_p + ggrid, 512, 0, stream>>>(
                    offsE, edges2, p_emb, M.oe, NS,
                    edges3, edges1, boffs4 + M.dodd * (NBMAX + 1), offsO,
                    nb_p, rsh_p, NP, mult8);
            // odd gather -> partial in e2 (free after gatherE)
            xcd_gather<<<8 * ((NP + 7) / 8), 256, 0, stream>>>(offsO, edges1,
                    s_emb, (float*)edges2, NP);
        }
        // final reduce for m1's odd output
        reduce8<<<(n4red + 255) / 256, 256, 0, stream>>>((const float*)edges2,
                mats[1].oo, n4red);
        return;
    }

    // ---- non-fused (ws-tight) path: r8 structure ----
    float* partial = (float*)edges1;
    const int ntiles = (nnz + TILE - 1) / TILE;
    struct Dir { const int* key; const int* other; const float* vals;
                 float* out; int odd; };
    Dir dirs[4] = {
        { a_rows,  a_cols,  a_vals,  out_sc,  0 },
        { a_cols,  a_rows,  a_vals,  out_pc,  1 },
        { ia_rows, ia_cols, ia_vals, out_sic, 0 },
        { ia_cols, ia_rows, ia_vals, out_pic, 1 },
    };
    for (int t = 0; t < 4; ++t) {
        const Dir& D = dirs[t];
        if (!D.odd) {
            staged_scatter<<<ntiles, 256, 0, stream>>>(D.key, D.other, D.vals,
                                                       bcur4 + t * NBMAX, edges1, nnz, rsh_s);
            row_sort1<<<nb_s, 512, 0, stream>>>(edges1, edges2,
                                                boffs4 + t * (NBMAX + 1), offsE,
                                                0, nb_s, rsh_s, NS, mult8);
            row_gather<<<(NS + 7) / 8, 256, 0, stream>>>(offsE, edges2, p_emb, D.out, NS);
        } else {
            staged_scatter<<<ntiles, 256, 0, stream>>>(D.key, D.other, D.vals,
                                                       bcur4 + t * NBMAX, edges1, nnz, rsh_p);
            row_sort1<<<nb_p, 512, 0, stream>>>(edges1, edges2,
                                                boffs4 + t * (NBMAX + 1), offsO,
                                                1, nb_p, rsh_p, NP, mult8);
            xcd_gather<<<8 * ((NP + 7) / 8), 256, 0, stream>>>(offsO, edges2,
                                                               s_emb, partial, NP);
            reduce8<<<(NP * 64 / 4 + 255) / 256, 256, 0, stream>>>(partial, D.out, NP * 64 / 4);
        }
    }
}

// Round 15
// 526.904 us; speedup vs baseline: 1.8417x; 1.0189x over previous
//
#include <hip/hip_runtime.h>
#include <hip/hip_bf16.h>

#define NBMAX 256   // coarse buckets per direction
#define TILE  4096  // edges per staged-scatter tile (per-dir fallback)
#define KPT   16    // TILE / 256
#define FTILE 2048  // edges per fused-scatter tile
#define FKPT  8     // FTILE / 256
#define BINSMAX 512 // max fine bins per bucket

// seg(student) in [0,8): near-uniform 8-way split via magic multiply
__device__ __forceinline__ int seg8(unsigned r, unsigned mult8) {
    return (int)__umulhi(r, mult8);
}

// ---------------- A1: coarse histogram, all 4 dirs (LDS-privatized) ---------
__global__ __launch_bounds__(256) void hist_all(
        const int* __restrict__ k0, const int* __restrict__ k1,
        const int* __restrict__ k2, const int* __restrict__ k3,
        int* __restrict__ gcnt4, int nnz, int rsh_s, int rsh_p) {
    __shared__ int h[NBMAX];
    int dir = blockIdx.x & 3;
    const int* key = (dir == 0) ? k0 : (dir == 1) ? k1 : (dir == 2) ? k2 : k3;
    int rsh = (dir & 1) ? rsh_p : rsh_s;
    h[threadIdx.x] = 0;
    __syncthreads();
    int ch = blockIdx.x >> 2, nch = gridDim.x >> 2;
    int nnz4 = nnz >> 2;
    for (int i = ch * 256 + threadIdx.x; i < nnz4; i += nch * 256) {
        int4 k4 = ((const int4*)key)[i];
        atomicAdd(&h[k4.x >> rsh], 1);
        atomicAdd(&h[k4.y >> rsh], 1);
        atomicAdd(&h[k4.z >> rsh], 1);
        atomicAdd(&h[k4.w >> rsh], 1);
    }
    if (ch == 0) {
        for (int i = (nnz4 << 2) + threadIdx.x; i < nnz; i += 256)
            atomicAdd(&h[key[i] >> rsh], 1);
    }
    __syncthreads();
    int v = h[threadIdx.x];
    if (v) atomicAdd(&gcnt4[dir * NBMAX + threadIdx.x], v);
}

// ---------------- A2: bucket offsets for all 4 dirs (4 blocks) --------------
__global__ __launch_bounds__(256) void scan_all(
        const int* __restrict__ gcnt4, int* __restrict__ boffs4,
        int* __restrict__ bcur4, int nb_s, int nb_p, int nnz,
        int* __restrict__ offsE, int* __restrict__ offsO, int NS, int NP8) {
    __shared__ int tmp[NBMAX];
    int dir = blockIdx.x, tid = threadIdx.x;
    int nb = (dir & 1) ? nb_p : nb_s;
    int v = (tid < nb) ? gcnt4[dir * NBMAX + tid] : 0;
    tmp[tid] = v;
    __syncthreads();
    for (int off = 1; off < NBMAX; off <<= 1) {
        int t = (tid >= off) ? tmp[tid - off] : 0;
        __syncthreads();
        tmp[tid] += t;
        __syncthreads();
    }
    if (tid < nb) {
        int e = tmp[tid] - v;
        boffs4[dir * (NBMAX + 1) + tid] = e;
        bcur4[dir * NBMAX + tid] = e;
    }
    if (tid == 0) boffs4[dir * (NBMAX + 1) + nb] = nnz;
    if (dir == 0 && tid == 0) { offsE[NS] = nnz; offsO[NP8] = nnz; }
}

// ---------------- A3a: per-dir staged scatter (fallback when ws is tight) ---
__global__ __launch_bounds__(256) void staged_scatter(
        const int* __restrict__ key, const int* __restrict__ other,
        const float* __restrict__ vals, int* __restrict__ cursor,
        uint2* __restrict__ edges, int nnz, int rsh) {
    __shared__ int lhist[NBMAX], lofs[NBMAX], lbase[NBMAX];
    __shared__ uint2 stage[TILE];
    __shared__ int   sslot[TILE];
    int tid = threadIdx.x;
    int lmask = (1 << rsh) - 1;
    int ntiles = (nnz + TILE - 1) / TILE;
    for (int tile = blockIdx.x; tile < ntiles; tile += gridDim.x) {
        int tbeg = tile * TILE;
        int n = nnz - tbeg; if (n > TILE) n = TILE;
        lhist[tid] = 0;
        __syncthreads();
        int myb[KPT], myr[KPT]; unsigned myo[KPT]; float myv[KPT];
        #pragma unroll
        for (int g = 0; g < 4; ++g) {
            int s = g * 1024 + tid * 4;
            if (s + 4 <= n) {
                int i = tbeg + s;
                int4   k4 = *(const int4*)(key + i);
                int4   o4 = *(const int4*)(other + i);
                float4 v4 = *(const float4*)(vals + i);
                int   kk[4] = {k4.x, k4.y, k4.z, k4.w};
                int   oo[4] = {o4.x, o4.y, o4.z, o4.w};
                float vv[4] = {v4.x, v4.y, v4.z, v4.w};
                #pragma unroll
                for (int k = 0; k < 4; ++k) {
                    int m = g * 4 + k;
                    myb[m] = kk[k] >> rsh;
                    myo[m] = (unsigned)oo[k] | ((unsigned)(kk[k] & lmask) << 16);
                    myv[m] = vv[k];
                    myr[m] = atomicAdd(&lhist[myb[m]], 1);
                }
            } else {
                #pragma unroll
                for (int k = 0; k < 4; ++k) {
                    int m = g * 4 + k;
                    int s2 = s + k;
                    if (s2 < n) {
                        int i = tbeg + s2;
                        int ky = key[i];
                        myb[m] = ky >> rsh;
                        myo[m] = (unsigned)other[i] | ((unsigned)(ky & lmask) << 16);
                        myv[m] = vals[i];
                        myr[m] = atomicAdd(&lhist[myb[m]], 1);
                    } else myb[m] = -1;
                }
            }
        }
        __syncthreads();
        int h = lhist[tid];
        lofs[tid] = h;
        __syncthreads();
        for (int off = 1; off < NBMAX; off <<= 1) {
            int t = (tid >= off) ? lofs[tid - off] : 0;
            __syncthreads();
            lofs[tid] += t;
            __syncthreads();
        }
        lofs[tid] -= h;
        if (h > 0) lbase[tid] = atomicAdd(&cursor[tid], h);
        __syncthreads();
        #pragma unroll
        for (int k = 0; k < KPT; ++k) {
            if (myb[k] >= 0) {
                int ls = lofs[myb[k]] + myr[k];
                stage[ls] = make_uint2(myo[k], __float_as_uint(myv[k]));
                sslot[ls] = lbase[myb[k]] + myr[k];
            }
        }
        __syncthreads();
        #pragma unroll
        for (int k = 0; k < KPT; ++k) {
            int s = k * 256 + tid;
            if (s < n) edges[sslot[s]] = stage[s];
        }
        __syncthreads();
    }
}

// ---------------- A3b: FUSED scatter (r10 form) + optional merged reduce ----
__global__ __launch_bounds__(256) void staged_scatter2(
        const int* __restrict__ krow, const int* __restrict__ kcol,
        const float* __restrict__ vals,
        int* __restrict__ curE, int* __restrict__ curO,
        uint2* __restrict__ edgesE, uint2* __restrict__ edgesO,
        int nnz, int rsh_e, int rsh_o, int sgrid,
        const float* __restrict__ rpart, float* __restrict__ rout, int n4red) {
    __shared__ int lhistE[NBMAX], lofsE[NBMAX], lbaseE[NBMAX];
    __shared__ int lhistO[NBMAX], lofsO[NBMAX], lbaseO[NBMAX];
    __shared__ uint2 stageE[FTILE], stageO[FTILE];
    __shared__ int   sslotE[FTILE], sslotO[FTILE];
    int tid = threadIdx.x;
    int nred = (n4red + 255) >> 8;
    if ((int)blockIdx.x < nred) {                  // merged reduce8 (prev mat)
        int i = blockIdx.x * 256 + tid;
        if (i < n4red) {
            const float4* p = (const float4*)rpart;
            float4 s = make_float4(0.f, 0.f, 0.f, 0.f);
            #pragma unroll
            for (int xx = 0; xx < 8; ++xx) {
                float4 v = p[(size_t)xx * n4red + i];
                s.x += v.x; s.y += v.y; s.z += v.z; s.w += v.w;
            }
            ((float4*)rout)[i] = s;
        }
        return;
    }
    int sb = blockIdx.x - nred;
    int lmE = (1 << rsh_e) - 1, lmO = (1 << rsh_o) - 1;
    int ntiles = (nnz + FTILE - 1) / FTILE;
    for (int tile = sb; tile < ntiles; tile += sgrid) {
        int tbeg = tile * FTILE;
        int n = nnz - tbeg; if (n > FTILE) n = FTILE;
        lhistE[tid] = 0; lhistO[tid] = 0;
        __syncthreads();
        int mbE[FKPT], mrE[FKPT]; unsigned moE[FKPT];
        int mbO[FKPT], mrO[FKPT]; unsigned moO[FKPT];
        float mv[FKPT];
        #pragma unroll
        for (int g = 0; g < 2; ++g) {
            int s = g * 1024 + tid * 4;           // 4 consecutive edges/thread
            if (s + 4 <= n) {
                int i = tbeg + s;
                int4   r4 = *(const int4*)(krow + i);
                int4   c4 = *(const int4*)(kcol + i);
                float4 v4 = *(const float4*)(vals + i);
                int   rr[4] = {r4.x, r4.y, r4.z, r4.w};
                int   cc[4] = {c4.x, c4.y, c4.z, c4.w};
                float vv[4] = {v4.x, v4.y, v4.z, v4.w};
                #pragma unroll
                for (int k = 0; k < 4; ++k) {
                    int m = g * 4 + k;
                    mv[m]  = vv[k];
                    mbE[m] = rr[k] >> rsh_e;
                    moE[m] = (unsigned)cc[k] | ((unsigned)(rr[k] & lmE) << 16);
                    mrE[m] = atomicAdd(&lhistE[mbE[m]], 1);
                    mbO[m] = cc[k] >> rsh_o;
                    moO[m] = (unsigned)rr[k] | ((unsigned)(cc[k] & lmO) << 16);
                    mrO[m] = atomicAdd(&lhistO[mbO[m]], 1);
                }
            } else {
                #pragma unroll
                for (int k = 0; k < 4; ++k) {
                    int m = g * 4 + k;
                    int s2 = s + k;
                    if (s2 < n) {
                        int i = tbeg + s2;
                        int r = krow[i], c = kcol[i];
                        mv[m]  = vals[i];
                        mbE[m] = r >> rsh_e;
                        moE[m] = (unsigned)c | ((unsigned)(r & lmE) << 16);
                        mrE[m] = atomicAdd(&lhistE[mbE[m]], 1);
                        mbO[m] = c >> rsh_o;
                        moO[m] = (unsigned)r | ((unsigned)(c & lmO) << 16);
                        mrO[m] = atomicAdd(&lhistO[mbO[m]], 1);
                    } else { mbE[m] = -1; mbO[m] = -1; }
                }
            }
        }
        __syncthreads();
        int hE = lhistE[tid], hO = lhistO[tid];
        lofsE[tid] = hE; lofsO[tid] = hO;
        __syncthreads();
        for (int off = 1; off < NBMAX; off <<= 1) {
            int tE = (tid >= off) ? lofsE[tid - off] : 0;
            int tO = (tid >= off) ? lofsO[tid - off] : 0;
            __syncthreads();
            lofsE[tid] += tE; lofsO[tid] += tO;
            __syncthreads();
        }
        lofsE[tid] -= hE; lofsO[tid] -= hO;
        if (hE > 0) lbaseE[tid] = atomicAdd(&curE[tid], hE);
        if (hO > 0) lbaseO[tid] = atomicAdd(&curO[tid], hO);
        __syncthreads();
        #pragma unroll
        for (int k = 0; k < FKPT; ++k) {
            if (mbE[k] >= 0) {
                int lsE = lofsE[mbE[k]] + mrE[k];
                stageE[lsE] = make_uint2(moE[k], __float_as_uint(mv[k]));
                sslotE[lsE] = lbaseE[mbE[k]] + mrE[k];
                int lsO = lofsO[mbO[k]] + mrO[k];
                stageO[lsO] = make_uint2(moO[k], __float_as_uint(mv[k]));
                sslotO[lsO] = lbaseO[mbO[k]] + mrO[k];
            }
        }
        __syncthreads();
        #pragma unroll
        for (int k = 0; k < FKPT; ++k) {
            int s = k * 256 + tid;
            if (s < n) {
                edgesE[sslotE[s]] = stageE[s];
                edgesO[sslotO[s]] = stageO[s];
            }
        }
        __syncthreads();
    }
}

// ---------------- sort body (shared by standalone + merged kernels) ---------
__device__ __forceinline__ void sort_body(
        const uint2* __restrict__ e1, uint2* __restrict__ e2,
        const int* __restrict__ boffs, int* __restrict__ offs,
        int odd, int b, int rsh, int nrows, unsigned mult8,
        int* cnt, int* tot) {
    int tid = threadIdx.x;
    int bins = odd ? (8 << rsh) : (1 << rsh);      // <= 512
    int beg = boffs[b], end = boffs[b + 1];
    if (tid < bins) cnt[tid] = 0;
    __syncthreads();
    for (int i = beg + tid; i < end; i += 512) {
        uint2 e = e1[i];
        int lrow = (int)(e.x >> 16);
        int bin = odd ? (lrow * 8 + seg8(e.x & 0xFFFFu, mult8)) : lrow;
        atomicAdd(&cnt[bin], 1);
    }
    __syncthreads();
    int own = (tid < bins) ? cnt[tid] : 0;
    tot[tid] = own;
    __syncthreads();
    for (int off = 1; off < 512; off <<= 1) {
        int t = (tid >= off) ? tot[tid - off] : 0;
        __syncthreads();
        tot[tid] += t;
        __syncthreads();
    }
    if (tid < bins) {
        int fineoff = tot[tid] - own;              // exclusive within bucket
        cnt[tid] = beg + fineoff;                  // becomes cursor
        if (!odd) {
            int row = (b << rsh) + tid;
            if (row < nrows) offs[row] = beg + fineoff;
        } else {
            int row = (b << rsh) + (tid >> 3);
            if (row < nrows) offs[(row << 3) + (tid & 7)] = beg + fineoff;
        }
    }
    __syncthreads();
    for (int i = beg + tid; i < end; i += 512) {
        uint2 e = e1[i];
        int lrow = (int)(e.x >> 16);
        int bin = odd ? (lrow * 8 + seg8(e.x & 0xFFFFu, mult8)) : lrow;
        int slot = atomicAdd(&cnt[bin], 1);
        e2[slot] = make_uint2(e.x & 0xFFFFu, e.y);
    }
}

// ---------------- B: one block per bucket, 2-pass fine sort (r8-proven) -----
__global__ __launch_bounds__(512) void row_sort1(
        const uint2* __restrict__ e1, uint2* __restrict__ e2,
        const int* __restrict__ boffs, int* __restrict__ offs,
        int odd, int nb, int rsh, int nrows, unsigned mult8) {
    __shared__ int cnt[BINSMAX];
    __shared__ int tot[512];
    int b = blockIdx.x;
    if (b >= nb) return;
    sort_body(e1, e2, boffs, offs, odd, b, rsh, nrows, mult8, cnt, tot);
}

// ---------------- gather core (r8 form - L2-BW-pinned, do not touch) --------
__device__ __forceinline__ void chunk_accum(
        float4& acc, uint2 e, int n, const float* __restrict__ xq, int q) {
    int   c0 = __shfl((int)e.x, q);
    float v0 = __uint_as_float(__shfl((int)e.y, q));
    int   c1 = __shfl((int)e.x, 4 + q);
    float v1 = __uint_as_float(__shfl((int)e.y, 4 + q));
    float4 x0 = *(const float4*)(xq + (((size_t)c0) << 6));
    float4 x1 = *(const float4*)(xq + (((size_t)c1) << 6));
    for (int j = 8; j < n; j += 8) {
        int   nc0 = __shfl((int)e.x, j + q);
        float nv0 = __uint_as_float(__shfl((int)e.y, j + q));
        int   nc1 = __shfl((int)e.x, j + 4 + q);
        float nv1 = __uint_as_float(__shfl((int)e.y, j + 4 + q));
        float4 nx0 = *(const float4*)(xq + (((size_t)nc0) << 6));
        float4 nx1 = *(const float4*)(xq + (((size_t)nc1) << 6));
        acc.x += v0 * x0.x; acc.y += v0 * x0.y;
        acc.z += v0 * x0.z; acc.w += v0 * x0.w;
        acc.x += v1 * x1.x; acc.y += v1 * x1.y;
        acc.z += v1 * x1.z; acc.w += v1 * x1.w;
        v0 = nv0; v1 = nv1; x0 = nx0; x1 = nx1;
    }
    acc.x += v0 * x0.x; acc.y += v0 * x0.y;
    acc.z += v0 * x0.z; acc.w += v0 * x0.w;
    acc.x += v1 * x1.x; acc.y += v1 * x1.y;
    acc.z += v1 * x1.z; acc.w += v1 * x1.w;
}

__device__ __forceinline__ float4 gather_pre(
        uint2 e0, int beg, int end, const uint2* __restrict__ edges,
        const float* __restrict__ xq, int q, int lane) {
    float4 acc = make_float4(0.f, 0.f, 0.f, 0.f);
    int n0 = end - beg; if (n0 > 64) n0 = 64;
    chunk_accum(acc, e0, n0, xq, q);              // empty bin: e0 zero -> +0
    for (int base = beg + 64; base < end; base += 64) {
        int n = end - base; if (n > 64) n = 64;
        uint2 e = make_uint2(0u, 0u);
        if (lane < n) e = edges[base + lane];
        chunk_accum(acc, e, n, xq, q);
    }
    acc.x += __shfl_xor(acc.x, 16); acc.y += __shfl_xor(acc.y, 16);
    acc.z += __shfl_xor(acc.z, 16); acc.w += __shfl_xor(acc.w, 16);
    acc.x += __shfl_xor(acc.x, 32); acc.y += __shfl_xor(acc.y, 32);
    acc.z += __shfl_xor(acc.z, 32); acc.w += __shfl_xor(acc.w, 32);
    return acc;
}

// ---------------- device body: even gather for one (block,wave) -------------
__device__ __forceinline__ void gatherE_body(
        int rA, const int* __restrict__ offs, const uint2* __restrict__ edges,
        const float* __restrict__ x, float* __restrict__ out, int nrows,
        int lane) {
    int q = lane >> 4, l16 = lane & 15;
    const float* xq = x + (l16 << 2);
    if (rA >= nrows) return;
    int rB = rA + 1;
    int begA = offs[rA], endA = offs[rA + 1];
    int begB = 0, endB = 0;
    if (rB < nrows) { begB = offs[rB]; endB = offs[rB + 1]; }
    int nA = endA - begA; if (nA > 64) nA = 64;
    int nB = endB - begB; if (nB > 64) nB = 64;
    uint2 eA = make_uint2(0u, 0u), eB = make_uint2(0u, 0u);
    if (lane < nA) eA = edges[begA + lane];
    if (lane < nB) eB = edges[begB + lane];     // in flight during A's compute
    float4 accA = gather_pre(eA, begA, endA, edges, xq, q, lane);
    if ((lane >> 4) == 0)
        *(float4*)(out + (((size_t)rA) << 6) + (l16 << 2)) = accA;
    if (rB < nrows) {
        float4 accB = gather_pre(eB, begB, endB, edges, xq, q, lane);
        if ((lane >> 4) == 0)
            *(float4*)(out + (((size_t)rB) << 6) + (l16 << 2)) = accB;
    }
}

// ---------------- device body: odd gather for one (bin-pair) ----------------
__device__ __forceinline__ void xcdO_body(
        int rA, int slot, const int* __restrict__ offs,
        const uint2* __restrict__ edges, const float* __restrict__ x,
        float* __restrict__ partial, int NP, int lane) {
    int q = lane >> 4, l16 = lane & 15;
    const float* xq = x + (l16 << 2);
    if (rA >= NP) return;
    int rB = rA + 1;
    int binA = rA * 8 + slot;
    int begA = offs[binA], endA = offs[binA + 1];
    int begB = 0, endB = 0;
    if (rB < NP) { int binB = rB * 8 + slot; begB = offs[binB]; endB = offs[binB + 1]; }
    int nA = endA - begA; if (nA > 64) nA = 64;
    int nB = endB - begB; if (nB > 64) nB = 64;
    uint2 eA = make_uint2(0u, 0u), eB = make_uint2(0u, 0u);
    if (lane < nA) eA = edges[begA + lane];
    if (lane < nB) eB = edges[begB + lane];
    float4 accA = gather_pre(eA, begA, endA, edges, xq, q, lane);
    if ((lane >> 4) == 0)
        *(float4*)(partial + (size_t)slot * NP * 64 + (((size_t)rA) << 6) + (l16 << 2)) = accA;
    if (rB < NP) {
        float4 accB = gather_pre(eB, begB, endB, edges, xq, q, lane);
        if ((lane >> 4) == 0)
            *(float4*)(partial + (size_t)slot * NP * 64 + (((size_t)rB) << 6) + (l16 << 2)) = accB;
    }
}

// ---------------- C-even standalone (fallback path) ----------------
__global__ __launch_bounds__(256) void row_gather(
        const int* __restrict__ offs, const uint2* __restrict__ edges,
        const float* __restrict__ x, float* __restrict__ out, int nrows) {
    int wave = threadIdx.x >> 6, lane = threadIdx.x & 63;
    gatherE_body(blockIdx.x * 8 + wave * 2, offs, edges, x, out, nrows, lane);
}

// ---------------- MERGED: sortO [0,nb) + reduce8 [nb,nb+nred) + gatherE -----
__global__ __launch_bounds__(512) void gatherE_sortO(
        const int* __restrict__ offsE_, const uint2* __restrict__ e2g,
        const float* __restrict__ xg, float* __restrict__ outg, int nrows,
        const uint2* __restrict__ e1s, uint2* __restrict__ e2s,
        const int* __restrict__ boffsS, int* __restrict__ offsS,
        int nb, int rsh, int nrowsS, unsigned mult8,
        const float* __restrict__ rpart, float* __restrict__ rout, int n4red) {
    int tid = threadIdx.x;
    int nred = (n4red + 511) >> 9;
    if ((int)blockIdx.x >= nb + nred) {            // ---- gather part ----
        int gb = blockIdx.x - nb - nred;
        int wave = tid >> 6, lane = tid & 63;
        gatherE_body(gb * 16 + wave * 2, offsE_, e2g, xg, outg, nrows, lane);
        return;
    }
    if ((int)blockIdx.x >= nb) {                   // ---- reduce part ----
        int i = (blockIdx.x - nb) * 512 + tid;
        if (i < n4red) {
            const float4* p = (const float4*)rpart;
            float4 s = make_float4(0.f, 0.f, 0.f, 0.f);
            #pragma unroll
            for (int xx = 0; xx < 8; ++xx) {
                float4 v = p[(size_t)xx * n4red + i];
                s.x += v.x; s.y += v.y; s.z += v.z; s.w += v.w;
            }
            ((float4*)rout)[i] = s;
        }
        return;
    }
    // ---- sortO part ----
    __shared__ int cnt[BINSMAX];
    __shared__ int tot[512];
    sort_body(e1s, e2s, boffsS, offsS, 1, blockIdx.x, rsh, nrowsS, mult8, cnt, tot);
}

// ---------------- MERGED: sortE(m1) [0,nb) + xcd_gather(m0) (rest) ----------
// Data-independent: sortE reads rawE(m1) e_in -> e_out; xcd reads sortedO(m0)
// + offsO -> partial. Both low-LDS (4KB) so gather-role blocks keep full
// occupancy (r14 lesson: the 55KB scatter could NOT host this merge).
__global__ __launch_bounds__(512) void sortE_xcd(
        const uint2* __restrict__ e_in, uint2* __restrict__ e_out,
        const int* __restrict__ boffsS, int* __restrict__ offsS,
        int nb, int rsh, int nrowsS, unsigned mult8,
        const int* __restrict__ offsO, const uint2* __restrict__ edgesO,
        const float* __restrict__ x, float* __restrict__ partial, int NP) {
    int tid = threadIdx.x;
    if ((int)blockIdx.x >= nb) {                   // ---- xcd part ----
        int xg = blockIdx.x - nb;
        int slot = xg & 7;
        int t = xg >> 3;
        int wave = tid >> 6, lane = tid & 63;
        xcdO_body(t * 16 + wave * 2, slot, offsO, edgesO, x, partial, NP, lane);
        return;
    }
    // ---- sortE part ----
    __shared__ int cnt[BINSMAX];
    __shared__ int tot[512];
    sort_body(e_in, e_out, boffsS, offsS, 0, blockIdx.x, rsh, nrowsS, mult8, cnt, tot);
}

// ---------------- C-odd standalone ----------------
__global__ __launch_bounds__(256) void xcd_gather(
        const int* __restrict__ offs, const uint2* __restrict__ edges,
        const float* __restrict__ x, float* __restrict__ partial, int NP) {
    int g = blockIdx.x;
    int slot = g & 7;
    int t = g >> 3;
    int wave = threadIdx.x >> 6, lane = threadIdx.x & 63;
    xcdO_body(t * 8 + wave * 2, slot, offs, edges, x, partial, NP, lane);
}

__global__ __launch_bounds__(256) void reduce8(
        const float* __restrict__ partial, float* __restrict__ out, int n4) {
    int i = blockIdx.x * 256 + threadIdx.x;
    if (i < n4) {
        const float4* p = (const float4*)partial;
        float4 s = make_float4(0.f, 0.f, 0.f, 0.f);
        #pragma unroll
        for (int xx = 0; xx < 8; ++xx) {
            float4 v = p[(size_t)xx * n4 + i];
            s.x += v.x; s.y += v.y; s.z += v.z; s.w += v.w;
        }
        ((float4*)out)[i] = s;
    }
}

// ---------------- fallback: atomic scatter ----------------
__global__ void spmm_scatter_kernel(const int* __restrict__ rows, const int* __restrict__ cols,
                                    const float* __restrict__ vals,
                                    const float* __restrict__ s_emb, const float* __restrict__ p_emb,
                                    float* __restrict__ out_s, float* __restrict__ out_p, int nnz) {
    long long t = (long long)blockIdx.x * blockDim.x + threadIdx.x;
    int e = (int)(t >> 6);
    int d = (int)(t & 63);
    if (e >= nnz) return;
    int r = rows[e];
    int c = cols[e];
    float v = vals[e];
    atomicAdd(&out_s[(size_t)r * 64 + d], v * p_emb[(size_t)c * 64 + d]);
    atomicAdd(&out_p[(size_t)c * 64 + d], v * s_emb[(size_t)r * 64 + d]);
}

// ---------------- host ----------------
extern "C" void kernel_launch(void* const* d_in, const int* in_sizes, int n_in,
                              void* d_out, int out_size, void* d_ws, size_t ws_size,
                              hipStream_t stream) {
    const float* s_emb   = (const float*)d_in[0];
    const float* p_emb   = (const float*)d_in[1];
    const int*   a_rows  = (const int*)d_in[2];
    const int*   a_cols  = (const int*)d_in[3];
    const float* a_vals  = (const float*)d_in[4];
    const int*   ia_rows = (const int*)d_in[5];
    const int*   ia_cols = (const int*)d_in[6];
    const float* ia_vals = (const float*)d_in[7];

    const int NS  = in_sizes[0] / 64;
    const int NP  = in_sizes[1] / 64;
    const int nnz = in_sizes[2];
    const int NP8 = NP * 8;

    float* out = (float*)d_out;
    float* out_sc  = out;
    float* out_sic = out_sc  + (size_t)NS * 64;
    float* out_pc  = out_sic + (size_t)NS * 64;
    float* out_pic = out_pc  + (size_t)NP * 64;

    int rsh_s = 0; while ((((long long)NS + (1LL << rsh_s) - 1) >> rsh_s) > NBMAX) rsh_s++;
    int rsh_p = 0; while ((((long long)NP + (1LL << rsh_p) - 1) >> rsh_p) > NBMAX) rsh_p++;
    int nb_s = (NS + (1 << rsh_s) - 1) >> rsh_s;
    int nb_p = (NP + (1 << rsh_p) - 1) >> rsh_p;
    unsigned mult8 = (unsigned)((8ULL << 32) / (unsigned)NS);

    const size_t edges_bytes = (size_t)nnz * sizeof(uint2);
    const size_t offsE_bytes = (size_t)(NS + 1) * sizeof(int);
    const size_t offsO_bytes = (size_t)(NP8 + 1) * sizeof(int);
    const size_t fixed_bytes = offsE_bytes + offsO_bytes
                      + (size_t)(4 * NBMAX + 4 * (NBMAX + 1) + 4 * NBMAX) * sizeof(int) + 256;
    const size_t need  = 2 * edges_bytes + fixed_bytes;
    const size_t need3 = 3 * edges_bytes + fixed_bytes;
    const size_t need5 = 5 * edges_bytes + fixed_bytes;
    const bool packable = (NS <= 0xFFFF) && (NP <= 0xFFFF) &&
                          ((1 << rsh_s) <= BINSMAX) && ((8 << rsh_p) <= BINSMAX) &&
                          (edges_bytes >= (size_t)NP8 * 64 * sizeof(float)) &&
                          ((NP * 64) % 4 == 0);

    if (ws_size < need || !packable) {
        hipMemsetAsync(d_out, 0, (size_t)out_size * sizeof(float), stream);
        const long long total = (long long)nnz * 64;
        const int grid = (int)((total + 255) / 256);
        spmm_scatter_kernel<<<grid, 256, 0, stream>>>(a_rows, a_cols, a_vals, s_emb, p_emb,
                                                      out_sc, out_pc, nnz);
        spmm_scatter_kernel<<<grid, 256, 0, stream>>>(ia_rows, ia_cols, ia_vals, s_emb, p_emb,
                                                      out_sic, out_pic, nnz);
        return;
    }

    const bool fused  = (ws_size >= need3);
    const bool fused5 = (ws_size >= need5);

    char* w = (char*)d_ws;
    uint2* edges1 = (uint2*)w;  w += edges_bytes;
    uint2* edges2 = (uint2*)w;  w += edges_bytes;
    uint2* edges3 = nullptr; uint2* edges4 = nullptr; uint2* edges5 = nullptr;
    if (fused)  { edges3 = (uint2*)w; w += edges_bytes; }
    if (fused5) { edges4 = (uint2*)w; w += edges_bytes;
                  edges5 = (uint2*)w; w += edges_bytes; }
    int*   offsE  = (int*)w;    w += offsE_bytes;
    int*   offsO  = (int*)w;    w += offsO_bytes;
    int*   gcnt4  = (int*)w;    w += 4 * NBMAX * sizeof(int);
    int*   boffs4 = (int*)w;    w += 4 * (NBMAX + 1) * sizeof(int);
    int*   bcur4  = (int*)w;

    hipMemsetAsync(gcnt4, 0, 4 * NBMAX * sizeof(int), stream);
    // dirs: 0 = a by row, 1 = a by col, 2 = ia by row, 3 = ia by col
    hist_all<<<1024, 256, 0, stream>>>(a_rows, a_cols, ia_rows, ia_cols,
                                       gcnt4, nnz, rsh_s, rsh_p);
    scan_all<<<4, 256, 0, stream>>>(gcnt4, boffs4, bcur4, nb_s, nb_p, nnz,
                                    offsE, offsO, NS, NP8);

    const int ntiles2 = (nnz + FTILE - 1) / FTILE;
    const int ggrid   = (NS + 15) / 16;            // gather blocks (16 rows ea)
    const int n4red   = NP * 64 / 4;
    const int nredG   = (n4red + 511) / 512;       // reduce blocks in gEsO

    if (fused5) {
        // m0: scatter E->e1, O->e2
        staged_scatter2<<<ntiles2, 256, 0, stream>>>(a_rows, a_cols, a_vals,
                bcur4 + 0 * NBMAX, bcur4 + 1 * NBMAX,
                edges1, edges2, nnz, rsh_s, rsh_p, ntiles2,
                nullptr, nullptr, 0);
        // sortE(m0): e1 -> e3
        row_sort1<<<nb_s, 512, 0, stream>>>(edges1, edges3,
                boffs4 + 0 * (NBMAX + 1), offsE, 0, nb_s, rsh_s, NS, mult8);
        // gatherE(m0) (e3) + sortO(m0): e2 -> e1
        gatherE_sortO<<<nb_p + ggrid, 512, 0, stream>>>(
                offsE, edges3, p_emb, out_sc, NS,
                edges2, edges1, boffs4 + 1 * (NBMAX + 1), offsO,
                nb_p, rsh_p, NP, mult8, nullptr, nullptr, 0);
        // m1: scatter E->e2, O->e4 (e1 = sortedO(m0) untouched)
        staged_scatter2<<<ntiles2, 256, 0, stream>>>(ia_rows, ia_cols, ia_vals,
                bcur4 + 2 * NBMAX, bcur4 + 3 * NBMAX,
                edges2, edges4, nnz, rsh_s, rsh_p, ntiles2,
                nullptr, nullptr, 0);
        // merged: sortE(m1) e2->e3 + xcd(m0) e1 -> partial e5
        const int xgrid = 8 * ((NP + 15) / 16);
        sortE_xcd<<<nb_s + xgrid, 512, 0, stream>>>(
                edges2, edges3, boffs4 + 2 * (NBMAX + 1), offsE,
                nb_s, rsh_s, NS, mult8,
                offsO, edges1, s_emb, (float*)edges5, NP);
        // gatherE(m1) (e3) + sortO(m1): e4 -> e2 + reduce8(m0): e5 -> out_pc
        gatherE_sortO<<<nb_p + nredG + ggrid, 512, 0, stream>>>(
                offsE, edges3, p_emb, out_sic, NS,
                edges4, edges2, boffs4 + 3 * (NBMAX + 1), offsO,
                nb_p, rsh_p, NP, mult8,
                (const float*)edges5, out_pc, n4red);
        // xcd(m1): e2 -> partial e1
        xcd_gather<<<8 * ((NP + 7) / 8), 256, 0, stream>>>(offsO, edges2,
                s_emb, (float*)edges1, NP);
        reduce8<<<(n4red + 255) / 256, 256, 0, stream>>>((const float*)edges1,
                out_pic, n4red);
        return;
    }

    if (fused) {
        const int nred = (n4red + 255) / 256;
        struct Mat { const int* r; const int* c; const float* v;
                     float* oe; float* oo; int de, dodd; };
        Mat mats[2] = {
            { a_rows,  a_cols,  a_vals,  out_sc,  out_pc,  0, 1 },
            { ia_rows, ia_cols, ia_vals, out_sic, out_pic, 2, 3 },
        };
        for (int m = 0; m < 2; ++m) {
            const Mat& M = mats[m];
            int red_n4 = (m == 1) ? n4red : 0;
            int red_blocks = (m == 1) ? nred : 0;
            staged_scatter2<<<ntiles2 + red_blocks, 256, 0, stream>>>(
                    M.r, M.c, M.v,
                    bcur4 + M.de * NBMAX, bcur4 + M.dodd * NBMAX,
                    edges1, edges3, nnz, rsh_s, rsh_p, ntiles2,
                    (const float*)edges2, mats[0].oo, red_n4);
            row_sort1<<<nb_s, 512, 0, stream>>>(edges1, edges2,
                    boffs4 + M.de * (NBMAX + 1), offsE, 0, nb_s, rsh_s, NS, mult8);
            gatherE_sortO<<<nb_p + ggrid, 512, 0, stream>>>(
                    offsE, edges2, p_emb, M.oe, NS,
                    edges3, edges1, boffs4 + M.dodd * (NBMAX + 1), offsO,
                    nb_p, rsh_p, NP, mult8, nullptr, nullptr, 0);
            xcd_gather<<<8 * ((NP + 7) / 8), 256, 0, stream>>>(offsO, edges1,
                    s_emb, (float*)edges2, NP);
        }
        reduce8<<<(n4red + 255) / 256, 256, 0, stream>>>((const float*)edges2,
                mats[1].oo, n4red);
        return;
    }

    // ---- non-fused (ws-tight) path: r8 structure ----
    float* partial = (float*)edges1;
    const int ntiles = (nnz + TILE - 1) / TILE;
    struct Dir { const int* key; const int* other; const float* vals;
                 float* out; int odd; };
    Dir dirs[4] = {
        { a_rows,  a_cols,  a_vals,  out_sc,  0 },
        { a_cols,  a_rows,  a_vals,  out_pc,  1 },
        { ia_rows, ia_cols, ia_vals, out_sic, 0 },
        { ia_cols, ia_rows, ia_vals, out_pic, 1 },
    };
    for (int t = 0; t < 4; ++t) {
        const Dir& D = dirs[t];
        if (!D.odd) {
            staged_scatter<<<ntiles, 256, 0, stream>>>(D.key, D.other, D.vals,
                                                       bcur4 + t * NBMAX, edges1, nnz, rsh_s);
            row_sort1<<<nb_s, 512, 0, stream>>>(edges1, edges2,
                                                boffs4 + t * (NBMAX + 1), offsE,
                                                0, nb_s, rsh_s, NS, mult8);
            row_gather<<<(NS + 7) / 8, 256, 0, stream>>>(offsE, edges2, p_emb, D.out, NS);
        } else {
            staged_scatter<<<ntiles, 256, 0, stream>>>(D.key, D.other, D.vals,
                                                       bcur4 + t * NBMAX, edges1, nnz, rsh_p);
            row_sort1<<<nb_p, 512, 0, stream>>>(edges1, edges2,
                                                boffs4 + t * (NBMAX + 1), offsO,
                                                1, nb_p, rsh_p, NP, mult8);
            xcd_gather<<<8 * ((NP + 7) / 8), 256, 0, stream>>>(offsO, edges2,
                                                               s_emb, partial, NP);
            reduce8<<<(NP * 64 / 4 + 255) / 256, 256, 0, stream>>>(partial, D.out, NP * 64 / 4);
        }
    }
}